// Round 7
// baseline (2070.735 us; speedup 1.0000x reference)
//
#include <hip/hip_runtime.h>
#include <math.h>

// ---- problem constants ----
#define D_      1024
#define DH_     64
#define H_      8
#define INNER_  512
#define L_      6
#define NL_     64
#define FF_     4096
#define B_      4
#define T_      8
#define FV_     1024          // F*V
#define BT_     32            // B*T
#define MROWS_  32768         // BT*FV
#define NKV_    1088          // FV + NL
#define KVROWS_ 34816         // BT*NKV
#define ZB_     256           // BT*H

typedef __bf16 bf16;
typedef __bf16 bf16x8 __attribute__((ext_vector_type(8)));
typedef __bf16 bf16x4 __attribute__((ext_vector_type(4)));
typedef float  f32x4  __attribute__((ext_vector_type(4)));

#define BARRIER() { asm volatile("" ::: "memory"); __builtin_amdgcn_s_barrier(); asm volatile("" ::: "memory"); }

// ---- helpers ----
__device__ __forceinline__ void gload_lds16(const bf16* g, bf16* l) {
    __builtin_amdgcn_global_load_lds(
        (const __attribute__((address_space(1))) unsigned int*)g,
        (__attribute__((address_space(3))) unsigned int*)l, 16, 0, 0);
}

__device__ __forceinline__ float wred_sum(float v) {
#pragma unroll
    for (int o = 32; o > 0; o >>= 1) v += __shfl_xor(v, o, 64);
    return v;
}

__device__ __forceinline__ float gelu_f(float x) {
    return 0.5f * x * (1.0f + erff(x * 0.70710678118654752440f));
}

// ---- xhat: LN-normalize (x + frame_embs[t]) once, no affine, bf16 out ----
__global__ __launch_bounds__(256) void xhat_k(const float* __restrict__ x,
                                              const float* __restrict__ fe,
                                              bf16* __restrict__ xhat) {
    __shared__ float red[8];
    int row = blockIdx.x;                // bt*FV + fv
    int t = (row >> 10) & 7;
    const float* xr = x + (size_t)row * D_;
    const float* fr_ = fe + (size_t)t * D_;
    int tid = threadIdx.x, c = tid * 4;
    float4 v = *(const float4*)(xr + c);
    float4 f = *(const float4*)(fr_ + c);
    v.x += f.x; v.y += f.y; v.z += f.z; v.w += f.w;
    float s = v.x + v.y + v.z + v.w;
    float ss = v.x * v.x + v.y * v.y + v.z * v.z + v.w * v.w;
    s = wred_sum(s); ss = wred_sum(ss);
    if ((tid & 63) == 0) { red[tid >> 6] = s; red[4 + (tid >> 6)] = ss; }
    __syncthreads();
    s = red[0] + red[1] + red[2] + red[3];
    ss = red[4] + red[5] + red[6] + red[7];
    float mean = s * (1.0f / D_);
    float rstd = rsqrtf(ss * (1.0f / D_) - mean * mean + 1e-5f);
    bf16x4 o;
    o[0] = (bf16)((v.x - mean) * rstd);
    o[1] = (bf16)((v.y - mean) * rstd);
    o[2] = (bf16)((v.z - mean) * rstd);
    o[3] = (bf16)((v.w - mean) * rstd);
    *(bf16x4*)(xhat + (size_t)row * D_ + c) = o;
}

// ---- lat init ----
__global__ __launch_bounds__(256) void latinit_k(const float* __restrict__ latents,
                                                 float* __restrict__ lat) {
    int row = blockIdx.x;
    int i = row & 63;
    int c = threadIdx.x * 4;
    float4 v = *(const float4*)(latents + (size_t)i * D_ + c);
    *(float4*)(lat + (size_t)row * D_ + c) = v;
}

// ---- row LayerNorm with affine: fp32 in, bf16 out ----
template<int OUTF>
__global__ __launch_bounds__(256) void ln_k(const float* __restrict__ in,
                                            const float* __restrict__ g,
                                            const float* __restrict__ b,
                                            void* __restrict__ out) {
    __shared__ float red[8];
    int row = blockIdx.x;
    const float* x = in + (size_t)row * D_;
    int tid = threadIdx.x, c = tid * 4;
    float4 v = *(const float4*)(x + c);
    float s = v.x + v.y + v.z + v.w;
    float ss = v.x * v.x + v.y * v.y + v.z * v.z + v.w * v.w;
    s = wred_sum(s); ss = wred_sum(ss);
    if ((tid & 63) == 0) { red[tid >> 6] = s; red[4 + (tid >> 6)] = ss; }
    __syncthreads();
    s = red[0] + red[1] + red[2] + red[3];
    ss = red[4] + red[5] + red[6] + red[7];
    float mean = s * (1.0f / D_);
    float rstd = rsqrtf(ss * (1.0f / D_) - mean * mean + 1e-5f);
    float4 gv = *(const float4*)(g + c);
    float4 bv = *(const float4*)(b + c);
    float o0 = (v.x - mean) * rstd * gv.x + bv.x;
    float o1 = (v.y - mean) * rstd * gv.y + bv.y;
    float o2 = (v.z - mean) * rstd * gv.z + bv.z;
    float o3 = (v.w - mean) * rstd * gv.w + bv.w;
    if (OUTF) {
        *(float4*)((float*)out + (size_t)row * D_ + c) = make_float4(o0, o1, o2, o3);
    } else {
        bf16x4 o; o[0] = (bf16)o0; o[1] = (bf16)o1; o[2] = (bf16)o2; o[3] = (bf16)o3;
        *(bf16x4*)((bf16*)out + (size_t)row * D_ + c) = o;
    }
}

// ---- accln: lat += sum of NP partials; LN(lat) -> out. OUTF 0: bf16 lnl; 1: fp32 out ----
template<int NP, int OUTF>
__global__ __launch_bounds__(256) void accln_k(float* __restrict__ lat,
                                               const float* __restrict__ p, long long s,
                                               const float* __restrict__ g,
                                               const float* __restrict__ b,
                                               void* __restrict__ out) {
    __shared__ float red[8];
    int row = blockIdx.x;
    int tid = threadIdx.x, c = tid * 4;
    float* lr = lat + (size_t)row * D_;
    float4 a = *(const float4*)(lr + c);
#pragma unroll
    for (int w = 0; w < NP; w++) {
        float4 x = *(const float4*)(p + (size_t)w * s + (size_t)row * D_ + c);
        a.x += x.x; a.y += x.y; a.z += x.z; a.w += x.w;
    }
    if (!OUTF) *(float4*)(lr + c) = a;
    float sm = a.x + a.y + a.z + a.w;
    float ss = a.x * a.x + a.y * a.y + a.z * a.z + a.w * a.w;
    sm = wred_sum(sm); ss = wred_sum(ss);
    if ((tid & 63) == 0) { red[tid >> 6] = sm; red[4 + (tid >> 6)] = ss; }
    __syncthreads();
    sm = red[0] + red[1] + red[2] + red[3];
    ss = red[4] + red[5] + red[6] + red[7];
    float mean = sm * (1.0f / D_);
    float rstd = rsqrtf(ss * (1.0f / D_) - mean * mean + 1e-5f);
    float4 gv = *(const float4*)(g + c);
    float4 bv = *(const float4*)(b + c);
    float o0 = (a.x - mean) * rstd * gv.x + bv.x;
    float o1 = (a.y - mean) * rstd * gv.y + bv.y;
    float o2 = (a.z - mean) * rstd * gv.z + bv.z;
    float o3 = (a.w - mean) * rstd * gv.w + bv.w;
    if (OUTF) {
        *(float4*)((float*)out + (size_t)row * D_ + c) = make_float4(o0, o1, o2, o3);
    } else {
        bf16x4 o; o[0] = (bf16)o0; o[1] = (bf16)o1; o[2] = (bf16)o2; o[3] = (bf16)o3;
        *(bf16x4*)((bf16*)out + (size_t)row * D_ + c) = o;
    }
}

// ---- fused weight prep: transpose fp32->bf16, one launch per layer ----
// WkvTg branch also accumulates bkv[n] += bm[k]*wkv[k][n] (tile already in LDS).
__device__ __forceinline__ void wt_tile(const float* __restrict__ in, int R, int C,
                                        bf16* __restrict__ out, int bx, int by,
                                        const float* __restrict__ sc,
                                        const float* __restrict__ bm,
                                        float* __restrict__ bkv) {
    __shared__ float t[32][33];
    int c0 = bx * 32, r0 = by * 32;
    int tx = threadIdx.x & 31, ty = threadIdx.x >> 5;
#pragma unroll
    for (int i = 0; i < 4; i++)
        t[ty + i * 8][tx] = in[(size_t)(r0 + ty + i * 8) * C + c0 + tx];
    __syncthreads();
    float scale = sc ? sc[r0 + tx] : 1.0f;
#pragma unroll
    for (int i = 0; i < 4; i++)
        out[(size_t)(c0 + ty + i * 8) * R + r0 + tx] = (bf16)(t[tx][ty + i * 8] * scale);
    if (bm && ty == 0) {
        float s = 0.0f;
#pragma unroll
        for (int r = 0; r < 32; r++) s += bm[r0 + r] * t[r][tx];
        atomicAdd(&bkv[c0 + tx], s);
    }
}

__global__ __launch_bounds__(256) void wprep_k(const float* __restrict__ wq,
                                               const float* __restrict__ wkv,
                                               const float* __restrict__ wo,
                                               const float* __restrict__ w1,
                                               const float* __restrict__ w2,
                                               const float* __restrict__ gm,
                                               const float* __restrict__ bm,
                                               float* __restrict__ bkv,
                                               bf16* __restrict__ BcatQ,   // rows 0..511
                                               bf16* __restrict__ BcatKV,  // rows 512..1535
                                               bf16* __restrict__ WkvTg,
                                               bf16* __restrict__ WoT,
                                               bf16* __restrict__ W1T,
                                               bf16* __restrict__ W2T) {
    int id = blockIdx.x;
    if (id < 512)            wt_tile(wq, D_, INNER_, BcatQ, id & 15, id >> 4, nullptr, nullptr, nullptr);
    else if (id < 1536)  { int i = id - 512;  wt_tile(wkv, D_, 2 * INNER_, BcatKV, i & 31, i >> 5, nullptr, nullptr, nullptr); }
    else if (id < 2560)  { int i = id - 1536; wt_tile(wkv, D_, 2 * INNER_, WkvTg, i & 31, i >> 5, gm, bm, bkv); }
    else if (id < 3072)  { int i = id - 2560; wt_tile(wo, INNER_, D_, WoT, i & 31, i >> 5, nullptr, nullptr, nullptr); }
    else if (id < 7168)  { int i = id - 3072; wt_tile(w1, D_, FF_, W1T, i & 127, i >> 7, nullptr, nullptr, nullptr); }
    else                 { int i = id - 7168; wt_tile(w2, FF_, D_, W2T, i & 31, i >> 5, nullptr, nullptr, nullptr); }
}

// ======== gemm_bd: 128x256 NT GEMM, A-only LDS (swizzled), B direct-to-reg ========
// 8 waves (2M x 4N), wave tile 64x64. LDS: 2 x 16 KB A dbuf. B frags loaded from
// global (L2-hot panels) with 1-tile lookahead ping-pong. vmcnt ledger: 10 issues
// per tile (8 B-loads + 2 A-gload_lds); steady-state wait vmcnt(10).
// MODE 0: KV epilogue (bias; cb<512 -> KVb ld512 padded rows; else vt transposed)
// MODE 3: bf16 gelu out.  MODE 4: fp32 split-K partial (czs stride).
template<int MODE>
__global__ __launch_bounds__(512, 1) void gemm_bd(const bf16* __restrict__ Ag, int lda,
                                                  const bf16* __restrict__ Bg, int ldb,
                                                  void* __restrict__ C, int ldc, int K,
                                                  const float* __restrict__ bias,
                                                  long long czs, void* __restrict__ C2) {
    __shared__ bf16 alds[2][8192];   // 2 x 16 KB
    const int tid = threadIdx.x;
    const int w = tid >> 6, lane = tid & 63;
    const int wm = w >> 2, wn = w & 3;
    const size_t m0 = (size_t)blockIdx.x * 128;
    const size_t n0 = (size_t)blockIdx.y * 256;
    const int klen = K / gridDim.z;
    const int koff = blockIdx.z * klen;
    const int nt = klen >> 6;
    const int fr = lane & 15, g = lane >> 4;

    // A staging: 1024 chunks (128 rows x 8 kchunks of 16B); 2 gloads of 512 chunks
    const int p0 = tid, p1 = 512 + tid;
    const int ar0 = p0 >> 3, ak0 = ((p0 & 7) ^ (ar0 & 7)) * 8;
    const int ar1 = p1 >> 3, ak1 = ((p1 & 7) ^ (ar1 & 7)) * 8;
    const bf16* gA0 = Ag + (m0 + ar0) * (size_t)lda + koff + ak0;
    const bf16* gA1 = Ag + (m0 + ar1) * (size_t)lda + koff + ak1;
    const int ld0 = w * 512;          // elems (u=0), wave-uniform
    const int ld1 = 4096 + w * 512;   // elems (u=1)

    // B per-lane base: row n0 + wn*64 + fr (+16j), k = koff + g*8 (+ks*32)
    const bf16* gB = Bg + (n0 + wn * 64 + fr) * (size_t)ldb + koff + g * 8;

    // A frag read geometry
    const int pK0 = (g ^ (fr & 7)) * 8;
    const int pK1 = ((4 + g) ^ (fr & 7)) * 8;
    const size_t aoff = (size_t)(wm * 64 + fr) * 64;

    f32x4 acc[4][4];
#pragma unroll
    for (int i = 0; i < 4; i++)
#pragma unroll
        for (int j = 0; j < 4; j++)
#pragma unroll
            for (int r = 0; r < 4; r++) acc[i][j][r] = 0.0f;

    bf16x8 b0[4][2], b1[4][2];

    auto STAGE_A = [&](int kt, int buf) {
        gload_lds16(gA0 + kt, alds[buf] + ld0);
        gload_lds16(gA1 + kt, alds[buf] + ld1);
    };
    auto LOADB = [&](int kt, bf16x8 (&bb)[4][2]) {
#pragma unroll
        for (int j = 0; j < 4; j++)
#pragma unroll
            for (int ks = 0; ks < 2; ks++)
                bb[j][ks] = *(const bf16x8*)(gB + (size_t)(16 * j) * ldb + kt + ks * 32);
    };
    auto TILE = [&](int t, int cur, bf16x8 (&bc)[4][2], bf16x8 (&bn)[4][2]) {
        const int kt1 = (t + 1) << 6;
        if (t + 1 < nt) {
            LOADB(kt1, bn);
            STAGE_A(kt1, cur ^ 1);
            asm volatile("s_waitcnt vmcnt(10)");
        } else {
            asm volatile("s_waitcnt vmcnt(0)");
        }
        BARRIER();
        const bf16* al = alds[cur];
        bf16x8 ar[4][2];
#pragma unroll
        for (int i = 0; i < 4; i++) {
            ar[i][0] = *(const bf16x8*)(al + aoff + i * 1024 + pK0);
            ar[i][1] = *(const bf16x8*)(al + aoff + i * 1024 + pK1);
        }
        __builtin_amdgcn_s_setprio(1);
#pragma unroll
        for (int i = 0; i < 4; i++)
#pragma unroll
            for (int j = 0; j < 4; j++) {
                acc[i][j] = __builtin_amdgcn_mfma_f32_16x16x32_bf16(ar[i][0], bc[j][0], acc[i][j], 0, 0, 0);
                acc[i][j] = __builtin_amdgcn_mfma_f32_16x16x32_bf16(ar[i][1], bc[j][1], acc[i][j], 0, 0, 0);
            }
        __builtin_amdgcn_s_setprio(0);
        BARRIER();
    };

    // prologue: tile 0 (B->b0, A->lds0)
    LOADB(0, b0);
    STAGE_A(0, 0);
    for (int t = 0; t < nt; t += 2) {
        TILE(t, 0, b0, b1);
        TILE(t + 1, 1, b1, b0);
    }

    // ---- epilogue ----
    const int fq = g * 4;
#pragma unroll
    for (int i = 0; i < 4; i++)
#pragma unroll
        for (int j = 0; j < 4; j++) {
            size_t cb = n0 + wn * 64 + j * 16 + fr;
            size_t mb = m0 + wm * 64 + i * 16 + fq;
            if (MODE == 0) {
                float bv = bias[cb];
                if (cb < 512) {
#pragma unroll
                    for (int r = 0; r < 4; r++) {
                        size_t m = mb + r;
                        size_t rb = m + ((m >> 10) << 6);
                        ((bf16*)C)[rb * 512 + cb] = (bf16)(acc[i][j][r] + bv);
                    }
                } else {
                    int hh = ((int)cb - 512) >> 6, dh = ((int)cb - 512) & 63;
                    size_t bt = mb >> 10, jl = mb & 1023;
                    bf16x4 v4;
#pragma unroll
                    for (int r = 0; r < 4; r++) v4[r] = (bf16)(acc[i][j][r] + bv);
                    *(bf16x4*)((bf16*)C2 + ((bt * 8 + hh) * 64 + dh) * (size_t)NKV_ + jl) = v4;
                }
            } else if (MODE == 4) {
#pragma unroll
                for (int r = 0; r < 4; r++)
                    ((float*)C + blockIdx.z * czs)[(mb + r) * (size_t)ldc + cb] = acc[i][j][r];
            } else {
#pragma unroll
                for (int r = 0; r < 4; r++)
                    ((bf16*)C)[(mb + r) * (size_t)ldc + cb] = (bf16)gelu_f(acc[i][j][r]);
            }
        }
}

// ---- 128x128 NT GEMM (swizzled LDS) — q/KV-lat merged GEMM only ----
// CMAP 3: cb<512 -> qb*scale; 512<=cb<1024 -> KVb K-part (ld 512, lat rows);
//         cb>=1024 -> vt transposed (lat rows).
template<int MODE, int CMAP>
__global__ __launch_bounds__(256) void gemm128(const bf16* __restrict__ A, int lda,
                                               const bf16* __restrict__ Bw, int ldb,
                                               void* __restrict__ C, int ldc,
                                               int K, float scale,
                                               long long czs, void* __restrict__ C2,
                                               void* __restrict__ C3) {
    __shared__ bf16 As[128 * 32];
    __shared__ bf16 Bs[128 * 32];
    const int tid = threadIdx.x;
    const int wave = tid >> 6;
    const int lane = tid & 63;
    const size_t m0 = (size_t)blockIdx.x * 128;
    const size_t n0 = (size_t)blockIdx.y * 128;
    const int wm = (wave >> 1) * 64;
    const int wn = (wave & 1) * 64;

    const int klen = K / gridDim.z;
    const int koff = blockIdx.z * klen;

    const int r0 = tid >> 2;
    const int c0 = ((tid & 3) ^ ((tid >> 3) & 3)) * 8;
    const bf16* ga0 = A + (m0 + r0) * lda + c0 + koff;
    const bf16* ga1 = A + (m0 + r0 + 64) * lda + c0 + koff;
    const bf16* gb0 = Bw + (n0 + r0) * ldb + c0 + koff;
    const bf16* gb1 = Bw + (n0 + r0 + 64) * ldb + c0 + koff;
    bf16* la0 = As + wave * 512;
    bf16* la1 = As + 2048 + wave * 512;
    bf16* lb0 = Bs + wave * 512;
    bf16* lb1 = Bs + 2048 + wave * 512;

    f32x4 acc[4][4];
#pragma unroll
    for (int i = 0; i < 4; i++)
#pragma unroll
        for (int j = 0; j < 4; j++)
#pragma unroll
            for (int r = 0; r < 4; r++) acc[i][j][r] = 0.0f;

    const int fr = lane & 15;
    const int q = lane >> 4;
    const int sw = (q ^ ((fr >> 1) & 3)) * 8;

    for (int kt = 0; kt < klen; kt += 32) {
        gload_lds16(ga0 + kt, la0);
        gload_lds16(ga1 + kt, la1);
        gload_lds16(gb0 + kt, lb0);
        gload_lds16(gb1 + kt, lb1);
        __syncthreads();
        bf16x8 af[4], bfv[4];
#pragma unroll
        for (int i = 0; i < 4; i++) {
            af[i]  = *(const bf16x8*)(As + (wm + i * 16 + fr) * 32 + sw);
            bfv[i] = *(const bf16x8*)(Bs + (wn + i * 16 + fr) * 32 + sw);
        }
#pragma unroll
        for (int i = 0; i < 4; i++)
#pragma unroll
            for (int j = 0; j < 4; j++)
                acc[i][j] = __builtin_amdgcn_mfma_f32_16x16x32_bf16(af[i], bfv[j], acc[i][j], 0, 0, 0);
        __syncthreads();
    }

    const int fq = (lane >> 4) * 4;
#pragma unroll
    for (int i = 0; i < 4; i++)
#pragma unroll
        for (int j = 0; j < 4; j++) {
            size_t cb = n0 + wn + j * 16 + fr;
            size_t mb = m0 + wm + i * 16 + fq;
            if (CMAP == 3) {
                if (cb < 512) {
#pragma unroll
                    for (int r = 0; r < 4; r++)
                        ((bf16*)C)[(mb + r) * 512 + cb] = (bf16)(acc[i][j][r] * scale);
                } else if (cb < 1024) {
#pragma unroll
                    for (int r = 0; r < 4; r++) {
                        size_t m = mb + r;
                        size_t rb = (m >> 6) * (size_t)NKV_ + 1024 + (m & 63);
                        ((bf16*)C2)[rb * 512 + (cb - 512)] = (bf16)acc[i][j][r];
                    }
                } else {
                    int hh = ((int)cb - 1024) >> 6, dh = ((int)cb - 1024) & 63;
                    size_t bt = mb >> 6, jl = 1024 + (mb & 63);
                    bf16x4 v4;
#pragma unroll
                    for (int r = 0; r < 4; r++) v4[r] = (bf16)acc[i][j][r];
                    *(bf16x4*)((bf16*)C3 + ((bt * 8 + hh) * 64 + dh) * (size_t)NKV_ + jl) = v4;
                }
            } else {
#pragma unroll
                for (int r = 0; r < 4; r++)
                    ((bf16*)C)[(mb + r) * ldc + cb] = (bf16)acc[i][j][r];
            }
        }
}

// ======== fused attention: QK^T + online softmax + PV, one block per z ========
__global__ __launch_bounds__(256, 2) void attn_k(const bf16* __restrict__ qb,
                                                 const bf16* __restrict__ KVb,
                                                 const bf16* __restrict__ vt,
                                                 bf16* __restrict__ ob) {
    __shared__ float comb[4][64 * 66];
    __shared__ float sc[4][64];
    __shared__ float mw[4][64], lw[4][64];
    const int z = blockIdx.x, bt = z >> 3, h = z & 7;
    const int tid = threadIdx.x, w = tid >> 6, lane = tid & 63;
    const int fr = lane & 15, g = lane >> 4;
    const bf16* Qz = qb + (size_t)(bt * 64) * INNER_ + h * DH_;
    const bf16* Kz = KVb + (size_t)bt * NKV_ * 512 + h * DH_;   // K rows, ld 512
    const bf16* Vz = vt + (size_t)z * (DH_ * NKV_);
    bf16* Pw = (bf16*)(&comb[w][0]);

    bf16x8 qf[4][2];
#pragma unroll
    for (int nj = 0; nj < 4; nj++)
#pragma unroll
        for (int ks = 0; ks < 2; ks++)
            qf[nj][ks] = *(const bf16x8*)(Qz + (size_t)(fr + 16 * nj) * INNER_ + g * 8 + ks * 32);

    f32x4 acc_o[4][4];
#pragma unroll
    for (int i = 0; i < 4; i++)
#pragma unroll
        for (int j = 0; j < 4; j++)
#pragma unroll
            for (int r = 0; r < 4; r++) acc_o[i][j][r] = 0.0f;
    float m_reg[4] = {-INFINITY, -INFINITY, -INFINITY, -INFINITY};
    float l_reg[4] = {0.0f, 0.0f, 0.0f, 0.0f};

    const int nch = (w == 0) ? 5 : 4;
    for (int ci = 0; ci < nch; ci++) {
        const int kc0 = (w + ci * 4) * 64;
        f32x4 s[4][4];
#pragma unroll
        for (int i = 0; i < 4; i++)
#pragma unroll
            for (int j = 0; j < 4; j++)
#pragma unroll
                for (int r = 0; r < 4; r++) s[i][j][r] = 0.0f;
#pragma unroll
        for (int ks = 0; ks < 2; ks++) {
            bf16x8 kf[4];
#pragma unroll
            for (int mi = 0; mi < 4; mi++)
                kf[mi] = *(const bf16x8*)(Kz + (size_t)(kc0 + fr + 16 * mi) * 512 + g * 8 + ks * 32);
#pragma unroll
            for (int mi = 0; mi < 4; mi++)
#pragma unroll
                for (int nj = 0; nj < 4; nj++)
                    s[mi][nj] = __builtin_amdgcn_mfma_f32_16x16x32_bf16(kf[mi], qf[nj][ks], s[mi][nj], 0, 0, 0);
        }
        float pmax[4];
#pragma unroll
        for (int nj = 0; nj < 4; nj++) {
            float mx = s[0][nj][0];
#pragma unroll
            for (int mi = 0; mi < 4; mi++)
#pragma unroll
                for (int r = 0; r < 4; r++) mx = fmaxf(mx, s[mi][nj][r]);
            mx = fmaxf(mx, __shfl_xor(mx, 16, 64));
            mx = fmaxf(mx, __shfl_xor(mx, 32, 64));
            pmax[nj] = mx;
        }
        bool grew = (pmax[0] > m_reg[0]) || (pmax[1] > m_reg[1]) ||
                    (pmax[2] > m_reg[2]) || (pmax[3] > m_reg[3]);
        if (__any(grew ? 1 : 0)) {
            float so[4];
#pragma unroll
            for (int nj = 0; nj < 4; nj++) {
                float mn = fmaxf(m_reg[nj], pmax[nj]);
                so[nj] = __expf(m_reg[nj] - mn);
                m_reg[nj] = mn;
                l_reg[nj] *= so[nj];
            }
            if (g == 0) {
#pragma unroll
                for (int nj = 0; nj < 4; nj++) sc[w][fr + 16 * nj] = so[nj];
            }
            asm volatile("s_waitcnt lgkmcnt(0)" ::: "memory");
#pragma unroll
            for (int mi = 0; mi < 4; mi++)
#pragma unroll
                for (int r = 0; r < 4; r++) {
                    float sq = sc[w][16 * mi + 4 * g + r];
#pragma unroll
                    for (int jd = 0; jd < 4; jd++) acc_o[mi][jd][r] *= sq;
                }
        }
        float psum[4] = {0.0f, 0.0f, 0.0f, 0.0f};
#pragma unroll
        for (int mi = 0; mi < 4; mi++)
#pragma unroll
            for (int nj = 0; nj < 4; nj++) {
                bf16x4 pb4;
#pragma unroll
                for (int r = 0; r < 4; r++) {
                    float pv = __expf(s[mi][nj][r] - m_reg[nj]);
                    psum[nj] += pv;
                    pb4[r] = (bf16)pv;
                }
                *(bf16x4*)(Pw + (size_t)(fr + 16 * nj) * 72 + 16 * mi + 4 * g) = pb4;
            }
#pragma unroll
        for (int nj = 0; nj < 4; nj++) {
            float ps = psum[nj];
            ps += __shfl_xor(ps, 16, 64);
            ps += __shfl_xor(ps, 32, 64);
            l_reg[nj] += ps;
        }
        asm volatile("s_waitcnt lgkmcnt(0)" ::: "memory");
#pragma unroll
        for (int ks = 0; ks < 2; ks++) {
            bf16x8 af[4], vf[4];
#pragma unroll
            for (int mi = 0; mi < 4; mi++)
                af[mi] = *(const bf16x8*)(Pw + (size_t)(fr + 16 * mi) * 72 + g * 8 + ks * 32);
#pragma unroll
            for (int jd = 0; jd < 4; jd++)
                vf[jd] = *(const bf16x8*)(Vz + (size_t)(fr + 16 * jd) * NKV_ + kc0 + g * 8 + ks * 32);
#pragma unroll
            for (int mi = 0; mi < 4; mi++)
#pragma unroll
                for (int jd = 0; jd < 4; jd++)
                    acc_o[mi][jd] = __builtin_amdgcn_mfma_f32_16x16x32_bf16(af[mi], vf[jd], acc_o[mi][jd], 0, 0, 0);
        }
    }

    if (g == 0) {
#pragma unroll
        for (int nj = 0; nj < 4; nj++) {
            mw[w][fr + 16 * nj] = m_reg[nj];
            lw[w][fr + 16 * nj] = l_reg[nj];
        }
    }
    asm volatile("s_waitcnt lgkmcnt(0)" ::: "memory");
#pragma unroll
    for (int mi = 0; mi < 4; mi++)
#pragma unroll
        for (int jd = 0; jd < 4; jd++)
#pragma unroll
            for (int r = 0; r < 4; r++)
                comb[w][(16 * mi + 4 * g + r) * 66 + fr + 16 * jd] = acc_o[mi][jd][r];
    __syncthreads();
    {
        int q = tid >> 2, d0 = (tid & 3) * 16;
        float M = fmaxf(fmaxf(mw[0][q], mw[1][q]), fmaxf(mw[2][q], mw[3][q]));
        float al[4], l = 0.0f;
#pragma unroll
        for (int ww = 0; ww < 4; ww++) { al[ww] = __expf(mw[ww][q] - M); l += al[ww] * lw[ww][q]; }
        float inv = 1.0f / l;
        bf16 outv[16];
#pragma unroll
        for (int dd = 0; dd < 16; dd++) {
            float o = 0.0f;
#pragma unroll
            for (int ww = 0; ww < 4; ww++) o += comb[ww][q * 66 + d0 + dd] * al[ww];
            outv[dd] = (bf16)(o * inv);
        }
        bf16* dst = ob + (size_t)(bt * 64 + q) * INNER_ + h * 64 + d0;
        *(bf16x8*)dst = *(bf16x8*)outv;
        *(bf16x8*)(dst + 8) = *(bf16x8*)(outv + 8);
    }
}

// ---- host side ----
extern "C" void kernel_launch(void* const* d_in, const int* in_sizes, int n_in,
                              void* d_out, int out_size, void* d_ws, size_t ws_size,
                              hipStream_t stream) {
    const float* x       = (const float*)d_in[0];
    const float* latents = (const float*)d_in[1];
    const float* fe      = (const float*)d_in[2];
    const float* g_media = (const float*)d_in[3];
    const float* b_media = (const float*)d_in[4];
    const float* g_lat   = (const float*)d_in[5];
    const float* b_lat   = (const float*)d_in[6];
    const float* Wq      = (const float*)d_in[7];
    const float* Wkv     = (const float*)d_in[8];
    const float* Wo      = (const float*)d_in[9];
    const float* g_ff    = (const float*)d_in[10];
    const float* b_ff    = (const float*)d_in[11];
    const float* W1      = (const float*)d_in[12];
    const float* W2      = (const float*)d_in[13];
    const float* g_out   = (const float*)d_in[14];
    const float* b_out   = (const float*)d_in[15];

    char* p = (char*)d_ws;
    auto alloc = [&](size_t bytes) { char* r = p; p += (bytes + 255) & ~(size_t)255; return r; };
    bf16*  xhat = (bf16*)alloc((size_t)MROWS_ * D_ * 2);          // 67 MB
    float* lat  = (float*)alloc((size_t)2048 * D_ * 4);           // 8 MB
    bf16*  lnl  = (bf16*)alloc((size_t)2048 * D_ * 2);            // 4 MB
    bf16*  qb   = (bf16*)alloc((size_t)2048 * INNER_ * 2);        // 2 MB
    bf16*  KVb  = (bf16*)alloc((size_t)KVROWS_ * 512 * 2);        // 36 MB (K-part only, ld 512)
    bf16*  vt   = (bf16*)alloc((size_t)ZB_ * DH_ * NKV_ * 2);     // 36 MB
    bf16*  ob   = (bf16*)alloc((size_t)2048 * INNER_ * 2);        // 2 MB
    bf16*  Bcat = (bf16*)alloc((size_t)1536 * D_ * 2);            // 3 MB
    bf16*  WkvTg= (bf16*)alloc((size_t)D_ * D_ * 2);
    bf16*  WoT  = (bf16*)alloc((size_t)D_ * INNER_ * 2);
    bf16*  W1T  = (bf16*)alloc((size_t)FF_ * D_ * 2);
    bf16*  W2T  = (bf16*)alloc((size_t)D_ * FF_ * 2);
    float* bkv  = (float*)alloc(1024 * 4);
    float* ffp  = (float*)alloc((size_t)4 * 2048 * D_ * 4);       // 32 MB
    bf16*  ffh  = vt;            // alias: vt dead once attn done (16.8 MB <= 35.7 MB)

    xhat_k<<<MROWS_, 256, 0, stream>>>(x, fe, xhat);
    latinit_k<<<2048, 256, 0, stream>>>(latents, lat);
    ln_k<0><<<2048, 256, 0, stream>>>(lat, g_lat, b_lat, lnl);   // layer-0 latent LN

    const long long PS = (long long)2048 * D_;

    for (int l = 0; l < L_; l++) {
        const float* gm = g_media + (size_t)l * D_;
        const float* bm = b_media + (size_t)l * D_;
        const float* gf = g_ff + (size_t)l * D_;
        const float* bf_ = b_ff + (size_t)l * D_;
        const float* wq = Wq + (size_t)l * D_ * INNER_;
        const float* wkv = Wkv + (size_t)l * D_ * 2 * INNER_;
        const float* wo = Wo + (size_t)l * INNER_ * D_;
        const float* w1 = W1 + (size_t)l * D_ * FF_;
        const float* w2 = W2 + (size_t)l * FF_ * D_;

        hipMemsetAsync(bkv, 0, 1024 * 4, stream);
        wprep_k<<<11264, 256, 0, stream>>>(wq, wkv, wo, w1, w2, gm, bm, bkv,
                                           Bcat, Bcat + (size_t)512 * D_, WkvTg, WoT, W1T, W2T);

        // KV x-part: K -> KVb, V -> vt (transposed), +bkv   [B-direct pipeline]
        gemm_bd<0><<<dim3(256, 4), 512, 0, stream>>>(
            xhat, D_, WkvTg, D_, KVb, 0, D_, bkv, 0, vt);
        // merged: q = (lnl@WqT)*scale; KV lat rows: K -> KVb, V -> vt
        gemm128<0, 3><<<dim3(16, 12), 256, 0, stream>>>(
            lnl, D_, Bcat, D_, qb, 0, D_, 0.125f, 0, KVb, vt);

        // fused attention -> ob
        attn_k<<<ZB_, 256, 0, stream>>>(qb, KVb, vt, ob);

        // Wo split-K 2 -> fp32 partials   [B-direct]
        gemm_bd<4><<<dim3(16, 4, 2), 512, 0, stream>>>(
            ob, INNER_, WoT, INNER_, ffp, D_, INNER_, nullptr, PS, nullptr);
        // lat += partials; lnl = LN(lat; gf,bf)
        accln_k<2, 0><<<2048, 256, 0, stream>>>(lat, ffp, PS, gf, bf_, lnl);

        // FF1: ffh = gelu(lnl @ W1T)   [B-direct]
        gemm_bd<3><<<dim3(16, 16), 512, 0, stream>>>(
            lnl, D_, W1T, D_, ffh, FF_, D_, nullptr, 0, nullptr);
        // FF2 split-K 4 -> fp32 partials   [B-direct]
        gemm_bd<4><<<dim3(16, 4, 4), 512, 0, stream>>>(
            ffh, FF_, W2T, FF_, ffp, D_, FF_, nullptr, PS, nullptr);
        // lat += partials; next-layer latent LN (or final LN -> d_out)
        if (l < L_ - 1) {
            accln_k<4, 0><<<2048, 256, 0, stream>>>(lat, ffp, PS,
                g_lat + (size_t)(l + 1) * D_, b_lat + (size_t)(l + 1) * D_, lnl);
        } else {
            accln_k<4, 1><<<2048, 256, 0, stream>>>(lat, ffp, PS, g_out, b_out, (float*)d_out);
        }
    }
}

// Round 8
// 1324.310 us; speedup vs baseline: 1.5636x; 1.5636x over previous
//
#include <hip/hip_runtime.h>
#include <math.h>

// ---- problem constants ----
#define D_      1024
#define DH_     64
#define H_      8
#define INNER_  512
#define L_      6
#define NL_     64
#define FF_     4096
#define B_      4
#define T_      8
#define FV_     1024          // F*V
#define BT_     32            // B*T
#define MROWS_  32768         // BT*FV
#define NKV_    1088          // FV + NL
#define KVROWS_ 34816         // BT*NKV
#define ZB_     256           // BT*H

typedef __bf16 bf16;
typedef __bf16 bf16x8 __attribute__((ext_vector_type(8)));
typedef __bf16 bf16x4 __attribute__((ext_vector_type(4)));
typedef float  f32x4  __attribute__((ext_vector_type(4)));

#define BARRIER() { asm volatile("" ::: "memory"); __builtin_amdgcn_s_barrier(); asm volatile("" ::: "memory"); }
// end-of-phase: pin ds_reads above, drain own LDS reads, then block barrier.
#define ENDPH() { __builtin_amdgcn_sched_barrier(0); asm volatile("s_waitcnt lgkmcnt(0)"); __builtin_amdgcn_sched_barrier(0); BARRIER(); }

// ---- helpers ----
__device__ __forceinline__ void gload_lds16(const bf16* g, bf16* l) {
    __builtin_amdgcn_global_load_lds(
        (const __attribute__((address_space(1))) unsigned int*)g,
        (__attribute__((address_space(3))) unsigned int*)l, 16, 0, 0);
}

__device__ __forceinline__ float wred_sum(float v) {
#pragma unroll
    for (int o = 32; o > 0; o >>= 1) v += __shfl_xor(v, o, 64);
    return v;
}

__device__ __forceinline__ float gelu_f(float x) {
    return 0.5f * x * (1.0f + erff(x * 0.70710678118654752440f));
}

// ---- xhat: LN-normalize (x + frame_embs[t]) once, no affine, bf16 out ----
__global__ __launch_bounds__(256) void xhat_k(const float* __restrict__ x,
                                              const float* __restrict__ fe,
                                              bf16* __restrict__ xhat) {
    __shared__ float red[8];
    int row = blockIdx.x;                // bt*FV + fv
    int t = (row >> 10) & 7;
    const float* xr = x + (size_t)row * D_;
    const float* fr_ = fe + (size_t)t * D_;
    int tid = threadIdx.x, c = tid * 4;
    float4 v = *(const float4*)(xr + c);
    float4 f = *(const float4*)(fr_ + c);
    v.x += f.x; v.y += f.y; v.z += f.z; v.w += f.w;
    float s = v.x + v.y + v.z + v.w;
    float ss = v.x * v.x + v.y * v.y + v.z * v.z + v.w * v.w;
    s = wred_sum(s); ss = wred_sum(ss);
    if ((tid & 63) == 0) { red[tid >> 6] = s; red[4 + (tid >> 6)] = ss; }
    __syncthreads();
    s = red[0] + red[1] + red[2] + red[3];
    ss = red[4] + red[5] + red[6] + red[7];
    float mean = s * (1.0f / D_);
    float rstd = rsqrtf(ss * (1.0f / D_) - mean * mean + 1e-5f);
    bf16x4 o;
    o[0] = (bf16)((v.x - mean) * rstd);
    o[1] = (bf16)((v.y - mean) * rstd);
    o[2] = (bf16)((v.z - mean) * rstd);
    o[3] = (bf16)((v.w - mean) * rstd);
    *(bf16x4*)(xhat + (size_t)row * D_ + c) = o;
}

// ---- lat init ----
__global__ __launch_bounds__(256) void latinit_k(const float* __restrict__ latents,
                                                 float* __restrict__ lat) {
    int row = blockIdx.x;
    int i = row & 63;
    int c = threadIdx.x * 4;
    float4 v = *(const float4*)(latents + (size_t)i * D_ + c);
    *(float4*)(lat + (size_t)row * D_ + c) = v;
}

// ---- row LayerNorm with affine: fp32 in, bf16 out ----
template<int OUTF>
__global__ __launch_bounds__(256) void ln_k(const float* __restrict__ in,
                                            const float* __restrict__ g,
                                            const float* __restrict__ b,
                                            void* __restrict__ out) {
    __shared__ float red[8];
    int row = blockIdx.x;
    const float* x = in + (size_t)row * D_;
    int tid = threadIdx.x, c = tid * 4;
    float4 v = *(const float4*)(x + c);
    float s = v.x + v.y + v.z + v.w;
    float ss = v.x * v.x + v.y * v.y + v.z * v.z + v.w * v.w;
    s = wred_sum(s); ss = wred_sum(ss);
    if ((tid & 63) == 0) { red[tid >> 6] = s; red[4 + (tid >> 6)] = ss; }
    __syncthreads();
    s = red[0] + red[1] + red[2] + red[3];
    ss = red[4] + red[5] + red[6] + red[7];
    float mean = s * (1.0f / D_);
    float rstd = rsqrtf(ss * (1.0f / D_) - mean * mean + 1e-5f);
    float4 gv = *(const float4*)(g + c);
    float4 bv = *(const float4*)(b + c);
    float o0 = (v.x - mean) * rstd * gv.x + bv.x;
    float o1 = (v.y - mean) * rstd * gv.y + bv.y;
    float o2 = (v.z - mean) * rstd * gv.z + bv.z;
    float o3 = (v.w - mean) * rstd * gv.w + bv.w;
    if (OUTF) {
        *(float4*)((float*)out + (size_t)row * D_ + c) = make_float4(o0, o1, o2, o3);
    } else {
        bf16x4 o; o[0] = (bf16)o0; o[1] = (bf16)o1; o[2] = (bf16)o2; o[3] = (bf16)o3;
        *(bf16x4*)((bf16*)out + (size_t)row * D_ + c) = o;
    }
}

// ---- accln: lat += sum of NP partials; LN(lat) -> out. OUTF 0: bf16 lnl; 1: fp32 out ----
template<int NP, int OUTF>
__global__ __launch_bounds__(256) void accln_k(float* __restrict__ lat,
                                               const float* __restrict__ p, long long s,
                                               const float* __restrict__ g,
                                               const float* __restrict__ b,
                                               void* __restrict__ out) {
    __shared__ float red[8];
    int row = blockIdx.x;
    int tid = threadIdx.x, c = tid * 4;
    float* lr = lat + (size_t)row * D_;
    float4 a = *(const float4*)(lr + c);
#pragma unroll
    for (int w = 0; w < NP; w++) {
        float4 x = *(const float4*)(p + (size_t)w * s + (size_t)row * D_ + c);
        a.x += x.x; a.y += x.y; a.z += x.z; a.w += x.w;
    }
    if (!OUTF) *(float4*)(lr + c) = a;
    float sm = a.x + a.y + a.z + a.w;
    float ss = a.x * a.x + a.y * a.y + a.z * a.z + a.w * a.w;
    sm = wred_sum(sm); ss = wred_sum(ss);
    if ((tid & 63) == 0) { red[tid >> 6] = sm; red[4 + (tid >> 6)] = ss; }
    __syncthreads();
    sm = red[0] + red[1] + red[2] + red[3];
    ss = red[4] + red[5] + red[6] + red[7];
    float mean = sm * (1.0f / D_);
    float rstd = rsqrtf(ss * (1.0f / D_) - mean * mean + 1e-5f);
    float4 gv = *(const float4*)(g + c);
    float4 bv = *(const float4*)(b + c);
    float o0 = (a.x - mean) * rstd * gv.x + bv.x;
    float o1 = (a.y - mean) * rstd * gv.y + bv.y;
    float o2 = (a.z - mean) * rstd * gv.z + bv.z;
    float o3 = (a.w - mean) * rstd * gv.w + bv.w;
    if (OUTF) {
        *(float4*)((float*)out + (size_t)row * D_ + c) = make_float4(o0, o1, o2, o3);
    } else {
        bf16x4 o; o[0] = (bf16)o0; o[1] = (bf16)o1; o[2] = (bf16)o2; o[3] = (bf16)o3;
        *(bf16x4*)((bf16*)out + (size_t)row * D_ + c) = o;
    }
}

// ---- fused weight prep (+ bkv accumulation in WkvTg branch) ----
__device__ __forceinline__ void wt_tile(const float* __restrict__ in, int R, int C,
                                        bf16* __restrict__ out, int bx, int by,
                                        const float* __restrict__ sc,
                                        const float* __restrict__ bm,
                                        float* __restrict__ bkv) {
    __shared__ float t[32][33];
    int c0 = bx * 32, r0 = by * 32;
    int tx = threadIdx.x & 31, ty = threadIdx.x >> 5;
#pragma unroll
    for (int i = 0; i < 4; i++)
        t[ty + i * 8][tx] = in[(size_t)(r0 + ty + i * 8) * C + c0 + tx];
    __syncthreads();
    float scale = sc ? sc[r0 + tx] : 1.0f;
#pragma unroll
    for (int i = 0; i < 4; i++)
        out[(size_t)(c0 + ty + i * 8) * R + r0 + tx] = (bf16)(t[tx][ty + i * 8] * scale);
    if (bm && ty == 0) {
        float s = 0.0f;
#pragma unroll
        for (int r = 0; r < 32; r++) s += bm[r0 + r] * t[r][tx];
        atomicAdd(&bkv[c0 + tx], s);
    }
}

__global__ __launch_bounds__(256) void wprep_k(const float* __restrict__ wq,
                                               const float* __restrict__ wkv,
                                               const float* __restrict__ wo,
                                               const float* __restrict__ w1,
                                               const float* __restrict__ w2,
                                               const float* __restrict__ gm,
                                               const float* __restrict__ bm,
                                               float* __restrict__ bkv,
                                               bf16* __restrict__ BcatQ,   // rows 0..511
                                               bf16* __restrict__ BcatKV,  // rows 512..1535
                                               bf16* __restrict__ WkvTg,
                                               bf16* __restrict__ WoT,
                                               bf16* __restrict__ W1T,
                                               bf16* __restrict__ W2T) {
    int id = blockIdx.x;
    if (id < 512)            wt_tile(wq, D_, INNER_, BcatQ, id & 15, id >> 4, nullptr, nullptr, nullptr);
    else if (id < 1536)  { int i = id - 512;  wt_tile(wkv, D_, 2 * INNER_, BcatKV, i & 31, i >> 5, nullptr, nullptr, nullptr); }
    else if (id < 2560)  { int i = id - 1536; wt_tile(wkv, D_, 2 * INNER_, WkvTg, i & 31, i >> 5, gm, bm, bkv); }
    else if (id < 3072)  { int i = id - 2560; wt_tile(wo, INNER_, D_, WoT, i & 31, i >> 5, nullptr, nullptr, nullptr); }
    else if (id < 7168)  { int i = id - 3072; wt_tile(w1, D_, FF_, W1T, i & 127, i >> 7, nullptr, nullptr, nullptr); }
    else                 { int i = id - 7168; wt_tile(w2, FF_, D_, W2T, i & 31, i >> 5, nullptr, nullptr, nullptr); }
}

// ======== KV GEMM: 256x256, pipelined-frag 4-phase schedule ========
// Phase p MFMAs rows {2p,2p+1} with frags prefetched in phase p-1; single
// barrier/phase; LDS reads overlap MFMA. vmcnt(4) at ph2-end guarantees
// A(t+1) landed before ph3 prefetches tile-t+1 frags (ledger in comments).
__global__ __launch_bounds__(512, 1) void gemm_kv(const bf16* __restrict__ Ag,
                                                  const bf16* __restrict__ Bg,
                                                  bf16* __restrict__ KVb,
                                                  bf16* __restrict__ vt,
                                                  const float* __restrict__ bias) {
    __shared__ bf16 lds[2][32768];   // [buf][Alo 0 | Ahi 8192 | Blo 16384 | Bhi 24576]
    const int lda = D_, ldb = D_;
    const int tid = threadIdx.x;
    const int w = tid >> 6, lane = tid & 63;
    const int wm = w >> 2, wn = w & 3;
    const size_t m0 = (size_t)blockIdx.x * 256;
    const size_t n0 = (size_t)blockIdx.y * 256;
    const int nt = 16;   // K=1024, BK=64

    const int p0 = (w * 2) * 64 + lane, p1 = p0 + 64;
    const int sr0 = p0 >> 3, sk0 = ((p0 & 7) ^ (sr0 & 7)) * 8;
    const int sr1 = p1 >> 3, sk1 = ((p1 & 7) ^ (sr1 & 7)) * 8;
    const int scw0 = (w * 2) * 512, scw1 = scw0 + 512;

    auto STAGE = [&](const bf16* g, int ld, size_t row0, int k0, bf16* bufb, int rb) {
        gload_lds16(g + (row0 + sr0) * (size_t)ld + k0 + sk0, bufb + rb + scw0);
        gload_lds16(g + (row0 + sr1) * (size_t)ld + k0 + sk1, bufb + rb + scw1);
    };

    const int fr = lane & 15;
    const int pK0 = (((lane >> 4)) ^ (fr & 7)) * 8;
    const int pK1 = ((4 + (lane >> 4)) ^ (fr & 7)) * 8;
    const size_t aoff = (size_t)(wm * 128 + fr) * 64;
    const size_t boff = 16384 + (size_t)(wn * 64 + fr) * 64;

    f32x4 acc[8][4];
#pragma unroll
    for (int i = 0; i < 8; i++)
#pragma unroll
        for (int j = 0; j < 4; j++)
#pragma unroll
            for (int r = 0; r < 4; r++) acc[i][j][r] = 0.0f;

    bf16x8 aX[4], aY[4], bA[4][2], bB[4][2];

    auto LDA2 = [&](const bf16* lb, int i0, bf16x8 (&d)[4]) {
        d[0] = *(const bf16x8*)(lb + aoff + (size_t)i0 * 1024 + pK0);
        d[1] = *(const bf16x8*)(lb + aoff + (size_t)i0 * 1024 + pK1);
        d[2] = *(const bf16x8*)(lb + aoff + (size_t)(i0 + 1) * 1024 + pK0);
        d[3] = *(const bf16x8*)(lb + aoff + (size_t)(i0 + 1) * 1024 + pK1);
    };
    auto LDB8 = [&](const bf16* lb, bf16x8 (&bb)[4][2]) {
#pragma unroll
        for (int j = 0; j < 4; j++) {
            bb[j][0] = *(const bf16x8*)(lb + boff + j * 1024 + pK0);
            bb[j][1] = *(const bf16x8*)(lb + boff + j * 1024 + pK1);
        }
    };
    auto MM2 = [&](int i0, bf16x8 (&a)[4], bf16x8 (&bb)[4][2]) {
        __builtin_amdgcn_s_setprio(1);
#pragma unroll
        for (int j = 0; j < 4; j++) {
            acc[i0][j]     = __builtin_amdgcn_mfma_f32_16x16x32_bf16(a[0], bb[j][0], acc[i0][j], 0, 0, 0);
            acc[i0][j]     = __builtin_amdgcn_mfma_f32_16x16x32_bf16(a[1], bb[j][1], acc[i0][j], 0, 0, 0);
            acc[i0 + 1][j] = __builtin_amdgcn_mfma_f32_16x16x32_bf16(a[2], bb[j][0], acc[i0 + 1][j], 0, 0, 0);
            acc[i0 + 1][j] = __builtin_amdgcn_mfma_f32_16x16x32_bf16(a[3], bb[j][1], acc[i0 + 1][j], 0, 0, 0);
        }
        __builtin_amdgcn_s_setprio(0);
    };

    // prologue: tile0 full + tile1 {Blo,Bhi,Alo} = 14 loads
    STAGE(Bg, ldb, n0,       0, lds[0], 16384);
    STAGE(Bg, ldb, n0 + 128, 0, lds[0], 24576);
    STAGE(Ag, lda, m0,       0, lds[0], 0);
    STAGE(Ag, lda, m0 + 128, 0, lds[0], 8192);
    STAGE(Bg, ldb, n0,       64, lds[1], 16384);
    STAGE(Bg, ldb, n0 + 128, 64, lds[1], 24576);
    STAGE(Ag, lda, m0,       64, lds[1], 0);
    asm volatile("s_waitcnt vmcnt(6)");   // tile0 (8 oldest) landed
    BARRIER();
    LDB8(lds[0], bA);
    LDA2(lds[0], 0, aX);                  // t0 ph0 frags

    auto tile4 = [&](const bf16* lb, bf16* lbn, bf16x8 (&BU)[4][2], bf16x8 (&BL)[4][2], int t) {
        bf16* lbw = (bf16*)lb;
        // ph0: MFMA rows 0-1 (aX); prefetch rows 2-3; stage Ahi(t+1)->other buf
        LDA2(lb, 2, aY);
        if (t + 1 < nt) STAGE(Ag, lda, m0 + 128, (t + 1) << 6, lbn, 8192);
        MM2(0, aX, BU);
        ENDPH();
        // ph1: rows 2-3 (aY); prefetch 4-5; stage Blo(t+2)->cur
        LDA2(lb, 4, aX);
        if (t + 2 < nt) STAGE(Bg, ldb, n0, (t + 2) << 6, lbw, 16384);
        MM2(2, aY, BU);
        ENDPH();
        // ph2: rows 4-5 (aX); prefetch 6-7; stage Bhi(t+2); tile-end vmcnt
        LDA2(lb, 6, aY);
        if (t + 2 < nt) STAGE(Bg, ldb, n0 + 128, (t + 2) << 6, lbw, 24576);
        MM2(4, aX, BU);
        __builtin_amdgcn_sched_barrier(0);
        asm volatile("s_waitcnt lgkmcnt(0)");
        __builtin_amdgcn_sched_barrier(0);
        // outstanding (oldest first): Alo(t+1), Ahi(t+1), Blo(t+2), Bhi(t+2) = 8 loads
        if (t < nt - 2)       { asm volatile("s_waitcnt vmcnt(4)"); }   // A(t+1) landed
        else if (t == nt - 2) { asm volatile("s_waitcnt vmcnt(0)"); }
        BARRIER();
        // ph3: rows 6-7 (aY); prefetch tile-t+1 ph0 frags from other buf; stage Alo(t+2)
        if (t + 1 < nt) { LDB8(lbn, BL); LDA2(lbn, 0, aX); }
        if (t + 2 < nt) STAGE(Ag, lda, m0, (t + 2) << 6, lbw, 0);
        MM2(6, aY, BU);
        ENDPH();
    };

    for (int t = 0; t < nt; t += 2) {
        tile4(lds[0], lds[1], bA, bB, t);
        tile4(lds[1], lds[0], bB, bA, t + 1);
    }

    // epilogue: K -> KVb (ld 512), V -> vt transposed
    const int fq = (lane >> 4) * 4;
#pragma unroll
    for (int i = 0; i < 8; i++)
#pragma unroll
        for (int j = 0; j < 4; j++) {
            size_t cb = n0 + wn * 64 + j * 16 + fr;
            float bv = bias[cb];
            size_t mb = m0 + wm * 128 + i * 16 + fq;
            if (cb < 512) {
#pragma unroll
                for (int r = 0; r < 4; r++) {
                    size_t m = mb + r;
                    size_t rb = m + ((m >> 10) << 6);
                    KVb[rb * 512 + cb] = (bf16)(acc[i][j][r] + bv);
                }
            } else {
                int hh = ((int)cb - 512) >> 6, dh = ((int)cb - 512) & 63;
                size_t bt = mb >> 10, jl = mb & 1023;
                bf16x4 v4;
#pragma unroll
                for (int r = 0; r < 4; r++) v4[r] = (bf16)(acc[i][j][r] + bv);
                *(bf16x4*)(vt + ((bt * 8 + hh) * 64 + dh) * (size_t)NKV_ + jl) = v4;
            }
        }
}

// ======== FF GEMM: 128x256, pipelined-frag 4-phase schedule ========
// MODE 3: bf16 gelu out. MODE 4: fp32 split-K partial (czs stride).
template<int MODE>
__global__ __launch_bounds__(512, 1) void gemm_ff(const bf16* __restrict__ Ag, int lda,
                                                  const bf16* __restrict__ Bg, int ldb,
                                                  void* __restrict__ C, int ldc,
                                                  int K, long long czs) {
    __shared__ bf16 lds[2][24576];   // [buf][A 0..8191 | Blo 8192 | Bhi 16384]
    const int tid = threadIdx.x;
    const int w = tid >> 6, lane = tid & 63;
    const int wm = w >> 2, wn = w & 3;
    const size_t m0 = (size_t)blockIdx.x * 128;
    const size_t n0 = (size_t)blockIdx.y * 256;
    const int klen = K / gridDim.z;
    const int koff = blockIdx.z * klen;
    const int nt = klen >> 6;

    const int p0 = (w * 2) * 64 + lane, p1 = p0 + 64;
    const int sr0 = p0 >> 3, sk0 = ((p0 & 7) ^ (sr0 & 7)) * 8;
    const int sr1 = p1 >> 3, sk1 = ((p1 & 7) ^ (sr1 & 7)) * 8;
    const int scw0 = (w * 2) * 512, scw1 = scw0 + 512;

    auto STAGE = [&](const bf16* g, int ld, size_t row0, int k0, bf16* bufb, int rb) {
        gload_lds16(g + (row0 + sr0) * (size_t)ld + k0 + sk0, bufb + rb + scw0);
        gload_lds16(g + (row0 + sr1) * (size_t)ld + k0 + sk1, bufb + rb + scw1);
    };

    const int fr = lane & 15;
    const int pK0 = (((lane >> 4)) ^ (fr & 7)) * 8;
    const int pK1 = ((4 + (lane >> 4)) ^ (fr & 7)) * 8;
    const size_t aoff = (size_t)(wm * 64 + fr) * 64;
    const size_t boff = 8192 + (size_t)(wn * 64 + fr) * 64;

    f32x4 acc[4][4];
#pragma unroll
    for (int i = 0; i < 4; i++)
#pragma unroll
        for (int j = 0; j < 4; j++)
#pragma unroll
            for (int r = 0; r < 4; r++) acc[i][j][r] = 0.0f;

    bf16x8 aX[2], aY[2], bA[4][2], bB[4][2];

    auto LDA1 = [&](const bf16* lb, int i0, bf16x8 (&d)[2]) {
        d[0] = *(const bf16x8*)(lb + aoff + (size_t)i0 * 1024 + pK0);
        d[1] = *(const bf16x8*)(lb + aoff + (size_t)i0 * 1024 + pK1);
    };
    auto LDB8 = [&](const bf16* lb, bf16x8 (&bb)[4][2]) {
#pragma unroll
        for (int j = 0; j < 4; j++) {
            bb[j][0] = *(const bf16x8*)(lb + boff + j * 1024 + pK0);
            bb[j][1] = *(const bf16x8*)(lb + boff + j * 1024 + pK1);
        }
    };
    auto MM1 = [&](int i0, bf16x8 (&a)[2], bf16x8 (&bb)[4][2]) {
        __builtin_amdgcn_s_setprio(1);
#pragma unroll
        for (int j = 0; j < 4; j++) {
            acc[i0][j] = __builtin_amdgcn_mfma_f32_16x16x32_bf16(a[0], bb[j][0], acc[i0][j], 0, 0, 0);
            acc[i0][j] = __builtin_amdgcn_mfma_f32_16x16x32_bf16(a[1], bb[j][1], acc[i0][j], 0, 0, 0);
        }
        __builtin_amdgcn_s_setprio(0);
    };

    // prologue: tile0 {A,Blo,Bhi} + tile1 {Blo,Bhi} = 10 loads
    STAGE(Ag, lda, m0,       koff,      lds[0], 0);
    STAGE(Bg, ldb, n0,       koff,      lds[0], 8192);
    STAGE(Bg, ldb, n0 + 128, koff,      lds[0], 16384);
    STAGE(Bg, ldb, n0,       koff + 64, lds[1], 8192);
    STAGE(Bg, ldb, n0 + 128, koff + 64, lds[1], 16384);
    asm volatile("s_waitcnt vmcnt(4)");   // tile0 landed
    BARRIER();
    LDB8(lds[0], bA);
    LDA1(lds[0], 0, aX);

    auto tile4 = [&](const bf16* lb, bf16* lbn, bf16x8 (&BU)[4][2], bf16x8 (&BL)[4][2], int t) {
        bf16* lbw = (bf16*)lb;
        // ph0: MFMA row 0; prefetch row 1; stage A(t+1)->other buf
        LDA1(lb, 1, aY);
        if (t + 1 < nt) STAGE(Ag, lda, m0, koff + ((t + 1) << 6), lbn, 0);
        MM1(0, aX, BU);
        ENDPH();
        // ph1: row 1; prefetch row 2; stage Blo(t+2)->cur
        LDA1(lb, 2, aX);
        if (t + 2 < nt) STAGE(Bg, ldb, n0, koff + ((t + 2) << 6), lbw, 8192);
        MM1(1, aY, BU);
        ENDPH();
        // ph2: row 2; prefetch row 3; stage Bhi(t+2); tile-end vmcnt
        LDA1(lb, 3, aY);
        if (t + 2 < nt) STAGE(Bg, ldb, n0 + 128, koff + ((t + 2) << 6), lbw, 16384);
        MM1(2, aX, BU);
        __builtin_amdgcn_sched_barrier(0);
        asm volatile("s_waitcnt lgkmcnt(0)");
        __builtin_amdgcn_sched_barrier(0);
        // outstanding: A(t+1), Blo(t+2), Bhi(t+2) = 6 loads
        if (t < nt - 2)       { asm volatile("s_waitcnt vmcnt(4)"); }   // A(t+1) landed
        else if (t == nt - 2) { asm volatile("s_waitcnt vmcnt(0)"); }
        BARRIER();
        // ph3: row 3; prefetch tile-t+1 ph0 frags
        if (t + 1 < nt) { LDB8(lbn, BL); LDA1(lbn, 0, aX); }
        MM1(3, aY, BU);
        ENDPH();
    };

    for (int t = 0; t < nt; t += 2) {
        tile4(lds[0], lds[1], bA, bB, t);
        tile4(lds[1], lds[0], bB, bA, t + 1);
    }

    const int fq = (lane >> 4) * 4;
#pragma unroll
    for (int i = 0; i < 4; i++)
#pragma unroll
        for (int j = 0; j < 4; j++) {
            size_t cb = n0 + wn * 64 + j * 16 + fr;
            size_t mb = m0 + wm * 64 + i * 16 + fq;
#pragma unroll
            for (int r = 0; r < 4; r++) {
                float v = acc[i][j][r];
                if (MODE == 4) {
                    ((float*)C + blockIdx.z * czs)[(mb + r) * (size_t)ldc + cb] = v;
                } else {
                    ((bf16*)C)[(mb + r) * (size_t)ldc + cb] = (bf16)gelu_f(v);
                }
            }
        }
}

// ---- 128x128 NT GEMM (swizzled LDS) ----
// MODE 4: fp32 store (split-K partial, czs stride).
// CMAP 3: cb<512 -> qb*scale; 512<=cb<1024 -> KVb K-part (ld 512, lat rows);
//         cb>=1024 -> vt transposed (lat rows).
template<int MODE, int CMAP>
__global__ __launch_bounds__(256) void gemm128(const bf16* __restrict__ A, int lda,
                                               const bf16* __restrict__ Bw, int ldb,
                                               void* __restrict__ C, int ldc,
                                               int K, float scale,
                                               long long czs, void* __restrict__ C2,
                                               void* __restrict__ C3) {
    __shared__ bf16 As[128 * 32];
    __shared__ bf16 Bs[128 * 32];
    const int tid = threadIdx.x;
    const int wave = tid >> 6;
    const int lane = tid & 63;
    const size_t m0 = (size_t)blockIdx.x * 128;
    const size_t n0 = (size_t)blockIdx.y * 128;
    const int wm = (wave >> 1) * 64;
    const int wn = (wave & 1) * 64;

    const int klen = K / gridDim.z;
    const int koff = blockIdx.z * klen;

    const int r0 = tid >> 2;
    const int c0 = ((tid & 3) ^ ((tid >> 3) & 3)) * 8;
    const bf16* ga0 = A + (m0 + r0) * lda + c0 + koff;
    const bf16* ga1 = A + (m0 + r0 + 64) * lda + c0 + koff;
    const bf16* gb0 = Bw + (n0 + r0) * ldb + c0 + koff;
    const bf16* gb1 = Bw + (n0 + r0 + 64) * ldb + c0 + koff;
    bf16* la0 = As + wave * 512;
    bf16* la1 = As + 2048 + wave * 512;
    bf16* lb0 = Bs + wave * 512;
    bf16* lb1 = Bs + 2048 + wave * 512;

    f32x4 acc[4][4];
#pragma unroll
    for (int i = 0; i < 4; i++)
#pragma unroll
        for (int j = 0; j < 4; j++)
#pragma unroll
            for (int r = 0; r < 4; r++) acc[i][j][r] = 0.0f;

    const int fr = lane & 15;
    const int q = lane >> 4;
    const int sw = (q ^ ((fr >> 1) & 3)) * 8;

    for (int kt = 0; kt < klen; kt += 32) {
        gload_lds16(ga0 + kt, la0);
        gload_lds16(ga1 + kt, la1);
        gload_lds16(gb0 + kt, lb0);
        gload_lds16(gb1 + kt, lb1);
        __syncthreads();
        bf16x8 af[4], bfv[4];
#pragma unroll
        for (int i = 0; i < 4; i++) {
            af[i]  = *(const bf16x8*)(As + (wm + i * 16 + fr) * 32 + sw);
            bfv[i] = *(const bf16x8*)(Bs + (wn + i * 16 + fr) * 32 + sw);
        }
#pragma unroll
        for (int i = 0; i < 4; i++)
#pragma unroll
            for (int j = 0; j < 4; j++)
                acc[i][j] = __builtin_amdgcn_mfma_f32_16x16x32_bf16(af[i], bfv[j], acc[i][j], 0, 0, 0);
        __syncthreads();
    }

    const int fq = (lane >> 4) * 4;
#pragma unroll
    for (int i = 0; i < 4; i++)
#pragma unroll
        for (int j = 0; j < 4; j++) {
            size_t cb = n0 + wn + j * 16 + fr;
            size_t mb = m0 + wm + i * 16 + fq;
            if (CMAP == 3) {
                if (cb < 512) {
#pragma unroll
                    for (int r = 0; r < 4; r++)
                        ((bf16*)C)[(mb + r) * 512 + cb] = (bf16)(acc[i][j][r] * scale);
                } else if (cb < 1024) {
#pragma unroll
                    for (int r = 0; r < 4; r++) {
                        size_t m = mb + r;
                        size_t rb = (m >> 6) * (size_t)NKV_ + 1024 + (m & 63);
                        ((bf16*)C2)[rb * 512 + (cb - 512)] = (bf16)acc[i][j][r];
                    }
                } else {
                    int hh = ((int)cb - 1024) >> 6, dh = ((int)cb - 1024) & 63;
                    size_t bt = mb >> 6, jl = 1024 + (mb & 63);
                    bf16x4 v4;
#pragma unroll
                    for (int r = 0; r < 4; r++) v4[r] = (bf16)acc[i][j][r];
                    *(bf16x4*)((bf16*)C3 + ((bt * 8 + hh) * 64 + dh) * (size_t)NKV_ + jl) = v4;
                }
            } else {
#pragma unroll
                for (int r = 0; r < 4; r++) {
                    float v = acc[i][j][r];
                    if (MODE == 4) {
                        ((float*)C + blockIdx.z * czs)[(mb + r) * ldc + cb] = v;
                    } else {
                        ((bf16*)C)[(mb + r) * ldc + cb] = (bf16)v;
                    }
                }
            }
        }
}

// ======== fused attention: QK^T + online softmax + PV, one block per z ========
__global__ __launch_bounds__(256, 2) void attn_k(const bf16* __restrict__ qb,
                                                 const bf16* __restrict__ KVb,
                                                 const bf16* __restrict__ vt,
                                                 bf16* __restrict__ ob) {
    __shared__ float comb[4][64 * 66];
    __shared__ float sc[4][64];
    __shared__ float mw[4][64], lw[4][64];
    const int z = blockIdx.x, bt = z >> 3, h = z & 7;
    const int tid = threadIdx.x, w = tid >> 6, lane = tid & 63;
    const int fr = lane & 15, g = lane >> 4;
    const bf16* Qz = qb + (size_t)(bt * 64) * INNER_ + h * DH_;
    const bf16* Kz = KVb + (size_t)bt * NKV_ * 512 + h * DH_;   // K rows, ld 512
    const bf16* Vz = vt + (size_t)z * (DH_ * NKV_);
    bf16* Pw = (bf16*)(&comb[w][0]);

    bf16x8 qf[4][2];
#pragma unroll
    for (int nj = 0; nj < 4; nj++)
#pragma unroll
        for (int ks = 0; ks < 2; ks++)
            qf[nj][ks] = *(const bf16x8*)(Qz + (size_t)(fr + 16 * nj) * INNER_ + g * 8 + ks * 32);

    f32x4 acc_o[4][4];
#pragma unroll
    for (int i = 0; i < 4; i++)
#pragma unroll
        for (int j = 0; j < 4; j++)
#pragma unroll
            for (int r = 0; r < 4; r++) acc_o[i][j][r] = 0.0f;
    float m_reg[4] = {-INFINITY, -INFINITY, -INFINITY, -INFINITY};
    float l_reg[4] = {0.0f, 0.0f, 0.0f, 0.0f};

    const int nch = (w == 0) ? 5 : 4;
    for (int ci = 0; ci < nch; ci++) {
        const int kc0 = (w + ci * 4) * 64;
        f32x4 s[4][4];
#pragma unroll
        for (int i = 0; i < 4; i++)
#pragma unroll
            for (int j = 0; j < 4; j++)
#pragma unroll
                for (int r = 0; r < 4; r++) s[i][j][r] = 0.0f;
#pragma unroll
        for (int ks = 0; ks < 2; ks++) {
            bf16x8 kf[4];
#pragma unroll
            for (int mi = 0; mi < 4; mi++)
                kf[mi] = *(const bf16x8*)(Kz + (size_t)(kc0 + fr + 16 * mi) * 512 + g * 8 + ks * 32);
#pragma unroll
            for (int mi = 0; mi < 4; mi++)
#pragma unroll
                for (int nj = 0; nj < 4; nj++)
                    s[mi][nj] = __builtin_amdgcn_mfma_f32_16x16x32_bf16(kf[mi], qf[nj][ks], s[mi][nj], 0, 0, 0);
        }
        float pmax[4];
#pragma unroll
        for (int nj = 0; nj < 4; nj++) {
            float mx = s[0][nj][0];
#pragma unroll
            for (int mi = 0; mi < 4; mi++)
#pragma unroll
                for (int r = 0; r < 4; r++) mx = fmaxf(mx, s[mi][nj][r]);
            mx = fmaxf(mx, __shfl_xor(mx, 16, 64));
            mx = fmaxf(mx, __shfl_xor(mx, 32, 64));
            pmax[nj] = mx;
        }
        bool grew = (pmax[0] > m_reg[0]) || (pmax[1] > m_reg[1]) ||
                    (pmax[2] > m_reg[2]) || (pmax[3] > m_reg[3]);
        if (__any(grew ? 1 : 0)) {
            float so[4];
#pragma unroll
            for (int nj = 0; nj < 4; nj++) {
                float mn = fmaxf(m_reg[nj], pmax[nj]);
                so[nj] = __expf(m_reg[nj] - mn);
                m_reg[nj] = mn;
                l_reg[nj] *= so[nj];
            }
            if (g == 0) {
#pragma unroll
                for (int nj = 0; nj < 4; nj++) sc[w][fr + 16 * nj] = so[nj];
            }
            asm volatile("s_waitcnt lgkmcnt(0)" ::: "memory");
#pragma unroll
            for (int mi = 0; mi < 4; mi++)
#pragma unroll
                for (int r = 0; r < 4; r++) {
                    float sq = sc[w][16 * mi + 4 * g + r];
#pragma unroll
                    for (int jd = 0; jd < 4; jd++) acc_o[mi][jd][r] *= sq;
                }
        }
        float psum[4] = {0.0f, 0.0f, 0.0f, 0.0f};
#pragma unroll
        for (int mi = 0; mi < 4; mi++)
#pragma unroll
            for (int nj = 0; nj < 4; nj++) {
                bf16x4 pb4;
#pragma unroll
                for (int r = 0; r < 4; r++) {
                    float pv = __expf(s[mi][nj][r] - m_reg[nj]);
                    psum[nj] += pv;
                    pb4[r] = (bf16)pv;
                }
                *(bf16x4*)(Pw + (size_t)(fr + 16 * nj) * 72 + 16 * mi + 4 * g) = pb4;
            }
#pragma unroll
        for (int nj = 0; nj < 4; nj++) {
            float ps = psum[nj];
            ps += __shfl_xor(ps, 16, 64);
            ps += __shfl_xor(ps, 32, 64);
            l_reg[nj] += ps;
        }
        asm volatile("s_waitcnt lgkmcnt(0)" ::: "memory");
#pragma unroll
        for (int ks = 0; ks < 2; ks++) {
            bf16x8 af[4], vf[4];
#pragma unroll
            for (int mi = 0; mi < 4; mi++)
                af[mi] = *(const bf16x8*)(Pw + (size_t)(fr + 16 * mi) * 72 + g * 8 + ks * 32);
#pragma unroll
            for (int jd = 0; jd < 4; jd++)
                vf[jd] = *(const bf16x8*)(Vz + (size_t)(fr + 16 * jd) * NKV_ + kc0 + g * 8 + ks * 32);
#pragma unroll
            for (int mi = 0; mi < 4; mi++)
#pragma unroll
                for (int jd = 0; jd < 4; jd++)
                    acc_o[mi][jd] = __builtin_amdgcn_mfma_f32_16x16x32_bf16(af[mi], vf[jd], acc_o[mi][jd], 0, 0, 0);
        }
    }

    if (g == 0) {
#pragma unroll
        for (int nj = 0; nj < 4; nj++) {
            mw[w][fr + 16 * nj] = m_reg[nj];
            lw[w][fr + 16 * nj] = l_reg[nj];
        }
    }
    asm volatile("s_waitcnt lgkmcnt(0)" ::: "memory");
#pragma unroll
    for (int mi = 0; mi < 4; mi++)
#pragma unroll
        for (int jd = 0; jd < 4; jd++)
#pragma unroll
            for (int r = 0; r < 4; r++)
                comb[w][(16 * mi + 4 * g + r) * 66 + fr + 16 * jd] = acc_o[mi][jd][r];
    __syncthreads();
    {
        int q = tid >> 2, d0 = (tid & 3) * 16;
        float M = fmaxf(fmaxf(mw[0][q], mw[1][q]), fmaxf(mw[2][q], mw[3][q]));
        float al[4], l = 0.0f;
#pragma unroll
        for (int ww = 0; ww < 4; ww++) { al[ww] = __expf(mw[ww][q] - M); l += al[ww] * lw[ww][q]; }
        float inv = 1.0f / l;
        bf16 outv[16];
#pragma unroll
        for (int dd = 0; dd < 16; dd++) {
            float o = 0.0f;
#pragma unroll
            for (int ww = 0; ww < 4; ww++) o += comb[ww][q * 66 + d0 + dd] * al[ww];
            outv[dd] = (bf16)(o * inv);
        }
        bf16* dst = ob + (size_t)(bt * 64 + q) * INNER_ + h * 64 + d0;
        *(bf16x8*)dst = *(bf16x8*)outv;
        *(bf16x8*)(dst + 8) = *(bf16x8*)(outv + 8);
    }
}

// ---- host side ----
extern "C" void kernel_launch(void* const* d_in, const int* in_sizes, int n_in,
                              void* d_out, int out_size, void* d_ws, size_t ws_size,
                              hipStream_t stream) {
    const float* x       = (const float*)d_in[0];
    const float* latents = (const float*)d_in[1];
    const float* fe      = (const float*)d_in[2];
    const float* g_media = (const float*)d_in[3];
    const float* b_media = (const float*)d_in[4];
    const float* g_lat   = (const float*)d_in[5];
    const float* b_lat   = (const float*)d_in[6];
    const float* Wq      = (const float*)d_in[7];
    const float* Wkv     = (const float*)d_in[8];
    const float* Wo      = (const float*)d_in[9];
    const float* g_ff    = (const float*)d_in[10];
    const float* b_ff    = (const float*)d_in[11];
    const float* W1      = (const float*)d_in[12];
    const float* W2      = (const float*)d_in[13];
    const float* g_out   = (const float*)d_in[14];
    const float* b_out   = (const float*)d_in[15];

    char* p = (char*)d_ws;
    auto alloc = [&](size_t bytes) { char* r = p; p += (bytes + 255) & ~(size_t)255; return r; };
    bf16*  xhat = (bf16*)alloc((size_t)MROWS_ * D_ * 2);          // 67 MB
    float* lat  = (float*)alloc((size_t)2048 * D_ * 4);           // 8 MB
    bf16*  lnl  = (bf16*)alloc((size_t)2048 * D_ * 2);            // 4 MB
    bf16*  qb   = (bf16*)alloc((size_t)2048 * INNER_ * 2);        // 2 MB
    bf16*  KVb  = (bf16*)alloc((size_t)KVROWS_ * 512 * 2);        // 36 MB (K-part only, ld 512)
    bf16*  vt   = (bf16*)alloc((size_t)ZB_ * DH_ * NKV_ * 2);     // 36 MB
    bf16*  ob   = (bf16*)alloc((size_t)2048 * INNER_ * 2);        // 2 MB
    bf16*  Bcat = (bf16*)alloc((size_t)1536 * D_ * 2);            // 3 MB
    bf16*  WkvTg= (bf16*)alloc((size_t)D_ * D_ * 2);
    bf16*  WoT  = (bf16*)alloc((size_t)D_ * INNER_ * 2);
    bf16*  W1T  = (bf16*)alloc((size_t)FF_ * D_ * 2);
    bf16*  W2T  = (bf16*)alloc((size_t)D_ * FF_ * 2);
    float* bkv  = (float*)alloc(1024 * 4);
    float* ffp  = (float*)alloc((size_t)4 * 2048 * D_ * 4);       // 32 MB
    bf16*  ffh  = vt;            // alias: vt dead once attn done (16.8 MB <= 35.7 MB)

    xhat_k<<<MROWS_, 256, 0, stream>>>(x, fe, xhat);
    latinit_k<<<2048, 256, 0, stream>>>(latents, lat);
    ln_k<0><<<2048, 256, 0, stream>>>(lat, g_lat, b_lat, lnl);   // layer-0 latent LN

    const long long PS = (long long)2048 * D_;

    for (int l = 0; l < L_; l++) {
        const float* gm = g_media + (size_t)l * D_;
        const float* bm = b_media + (size_t)l * D_;
        const float* gf = g_ff + (size_t)l * D_;
        const float* bf_ = b_ff + (size_t)l * D_;
        const float* wq = Wq + (size_t)l * D_ * INNER_;
        const float* wkv = Wkv + (size_t)l * D_ * 2 * INNER_;
        const float* wo = Wo + (size_t)l * INNER_ * D_;
        const float* w1 = W1 + (size_t)l * D_ * FF_;
        const float* w2 = W2 + (size_t)l * FF_ * D_;

        hipMemsetAsync(bkv, 0, 1024 * 4, stream);
        wprep_k<<<11264, 256, 0, stream>>>(wq, wkv, wo, w1, w2, gm, bm, bkv,
                                           Bcat, Bcat + (size_t)512 * D_, WkvTg, WoT, W1T, W2T);

        // KV x-part: K -> KVb, V -> vt (transposed), +bkv   [pipelined 256²]
        gemm_kv<<<dim3(128, 4), 512, 0, stream>>>(xhat, WkvTg, KVb, vt, bkv);
        // merged: q = (lnl@WqT)*scale; KV lat rows: K -> KVb, V -> vt
        gemm128<0, 3><<<dim3(16, 12), 256, 0, stream>>>(
            lnl, D_, Bcat, D_, qb, 0, D_, 0.125f, 0, KVb, vt);

        // fused attention -> ob
        attn_k<<<ZB_, 256, 0, stream>>>(qb, KVb, vt, ob);

        // Wo split-K 2 -> fp32 partials
        gemm128<4, 0><<<dim3(16, 8, 2), 256, 0, stream>>>(
            ob, INNER_, WoT, INNER_, ffp, D_, INNER_, 1.0f, PS, nullptr, nullptr);
        // lat += partials; lnl = LN(lat; gf,bf)
        accln_k<2, 0><<<2048, 256, 0, stream>>>(lat, ffp, PS, gf, bf_, lnl);

        // FF1: ffh = gelu(lnl @ W1T)   [pipelined 128x256]
        gemm_ff<3><<<dim3(16, 16), 512, 0, stream>>>(
            lnl, D_, W1T, D_, ffh, FF_, D_, 0);
        // FF2 split-K 4 -> fp32 partials   [pipelined 128x256]
        gemm_ff<4><<<dim3(16, 4, 4), 512, 0, stream>>>(
            ffh, FF_, W2T, FF_, ffp, D_, FF_, PS);
        // lat += partials; next-layer latent LN (or final LN -> d_out)
        if (l < L_ - 1) {
            accln_k<4, 0><<<2048, 256, 0, stream>>>(lat, ffp, PS,
                g_lat + (size_t)(l + 1) * D_, b_lat + (size_t)(l + 1) * D_, lnl);
        } else {
            accln_k<4, 1><<<2048, 256, 0, stream>>>(lat, ffp, PS, g_out, b_out, (float*)d_out);
        }
    }
}

// Round 9
// 1279.591 us; speedup vs baseline: 1.6183x; 1.0349x over previous
//
#include <hip/hip_runtime.h>
#include <math.h>

// ---- problem constants ----
#define D_      1024
#define DH_     64
#define H_      8
#define INNER_  512
#define L_      6
#define NL_     64
#define FF_     4096
#define B_      4
#define T_      8
#define FV_     1024          // F*V
#define BT_     32            // B*T
#define MROWS_  32768         // BT*FV
#define NKV_    1088          // FV + NL
#define KVROWS_ 34816         // BT*NKV
#define ZB_     256           // BT*H

typedef __bf16 bf16;
typedef __bf16 bf16x8 __attribute__((ext_vector_type(8)));
typedef __bf16 bf16x4 __attribute__((ext_vector_type(4)));
typedef float  f32x4  __attribute__((ext_vector_type(4)));

#define BARRIER() { asm volatile("" ::: "memory"); __builtin_amdgcn_s_barrier(); asm volatile("" ::: "memory"); }
// end-of-phase (FF pipelined schedule): pin ds_reads above, drain, barrier.
#define ENDPH() { __builtin_amdgcn_sched_barrier(0); asm volatile("s_waitcnt lgkmcnt(0)"); __builtin_amdgcn_sched_barrier(0); BARRIER(); }

// ---- helpers ----
__device__ __forceinline__ void gload_lds16(const bf16* g, bf16* l) {
    __builtin_amdgcn_global_load_lds(
        (const __attribute__((address_space(1))) unsigned int*)g,
        (__attribute__((address_space(3))) unsigned int*)l, 16, 0, 0);
}

__device__ __forceinline__ float wred_sum(float v) {
#pragma unroll
    for (int o = 32; o > 0; o >>= 1) v += __shfl_xor(v, o, 64);
    return v;
}

__device__ __forceinline__ float gelu_f(float x) {
    return 0.5f * x * (1.0f + erff(x * 0.70710678118654752440f));
}

// ---- xhat: LN-normalize (x + frame_embs[t]) once, no affine, bf16 out ----
__global__ __launch_bounds__(256) void xhat_k(const float* __restrict__ x,
                                              const float* __restrict__ fe,
                                              bf16* __restrict__ xhat) {
    __shared__ float red[8];
    int row = blockIdx.x;                // bt*FV + fv
    int t = (row >> 10) & 7;
    const float* xr = x + (size_t)row * D_;
    const float* fr_ = fe + (size_t)t * D_;
    int tid = threadIdx.x, c = tid * 4;
    float4 v = *(const float4*)(xr + c);
    float4 f = *(const float4*)(fr_ + c);
    v.x += f.x; v.y += f.y; v.z += f.z; v.w += f.w;
    float s = v.x + v.y + v.z + v.w;
    float ss = v.x * v.x + v.y * v.y + v.z * v.z + v.w * v.w;
    s = wred_sum(s); ss = wred_sum(ss);
    if ((tid & 63) == 0) { red[tid >> 6] = s; red[4 + (tid >> 6)] = ss; }
    __syncthreads();
    s = red[0] + red[1] + red[2] + red[3];
    ss = red[4] + red[5] + red[6] + red[7];
    float mean = s * (1.0f / D_);
    float rstd = rsqrtf(ss * (1.0f / D_) - mean * mean + 1e-5f);
    bf16x4 o;
    o[0] = (bf16)((v.x - mean) * rstd);
    o[1] = (bf16)((v.y - mean) * rstd);
    o[2] = (bf16)((v.z - mean) * rstd);
    o[3] = (bf16)((v.w - mean) * rstd);
    *(bf16x4*)(xhat + (size_t)row * D_ + c) = o;
}

// ---- lat init ----
__global__ __launch_bounds__(256) void latinit_k(const float* __restrict__ latents,
                                                 float* __restrict__ lat) {
    int row = blockIdx.x;
    int i = row & 63;
    int c = threadIdx.x * 4;
    float4 v = *(const float4*)(latents + (size_t)i * D_ + c);
    *(float4*)(lat + (size_t)row * D_ + c) = v;
}

// ---- row LayerNorm with affine: fp32 in, bf16 out ----
template<int OUTF>
__global__ __launch_bounds__(256) void ln_k(const float* __restrict__ in,
                                            const float* __restrict__ g,
                                            const float* __restrict__ b,
                                            void* __restrict__ out) {
    __shared__ float red[8];
    int row = blockIdx.x;
    const float* x = in + (size_t)row * D_;
    int tid = threadIdx.x, c = tid * 4;
    float4 v = *(const float4*)(x + c);
    float s = v.x + v.y + v.z + v.w;
    float ss = v.x * v.x + v.y * v.y + v.z * v.z + v.w * v.w;
    s = wred_sum(s); ss = wred_sum(ss);
    if ((tid & 63) == 0) { red[tid >> 6] = s; red[4 + (tid >> 6)] = ss; }
    __syncthreads();
    s = red[0] + red[1] + red[2] + red[3];
    ss = red[4] + red[5] + red[6] + red[7];
    float mean = s * (1.0f / D_);
    float rstd = rsqrtf(ss * (1.0f / D_) - mean * mean + 1e-5f);
    float4 gv = *(const float4*)(g + c);
    float4 bv = *(const float4*)(b + c);
    float o0 = (v.x - mean) * rstd * gv.x + bv.x;
    float o1 = (v.y - mean) * rstd * gv.y + bv.y;
    float o2 = (v.z - mean) * rstd * gv.z + bv.z;
    float o3 = (v.w - mean) * rstd * gv.w + bv.w;
    if (OUTF) {
        *(float4*)((float*)out + (size_t)row * D_ + c) = make_float4(o0, o1, o2, o3);
    } else {
        bf16x4 o; o[0] = (bf16)o0; o[1] = (bf16)o1; o[2] = (bf16)o2; o[3] = (bf16)o3;
        *(bf16x4*)((bf16*)out + (size_t)row * D_ + c) = o;
    }
}

// ---- accln: lat += sum of NP partials; LN(lat) -> out. OUTF 0: bf16 lnl; 1: fp32 out ----
template<int NP, int OUTF>
__global__ __launch_bounds__(256) void accln_k(float* __restrict__ lat,
                                               const float* __restrict__ p, long long s,
                                               const float* __restrict__ g,
                                               const float* __restrict__ b,
                                               void* __restrict__ out) {
    __shared__ float red[8];
    int row = blockIdx.x;
    int tid = threadIdx.x, c = tid * 4;
    float* lr = lat + (size_t)row * D_;
    float4 a = *(const float4*)(lr + c);
#pragma unroll
    for (int w = 0; w < NP; w++) {
        float4 x = *(const float4*)(p + (size_t)w * s + (size_t)row * D_ + c);
        a.x += x.x; a.y += x.y; a.z += x.z; a.w += x.w;
    }
    if (!OUTF) *(float4*)(lr + c) = a;
    float sm = a.x + a.y + a.z + a.w;
    float ss = a.x * a.x + a.y * a.y + a.z * a.z + a.w * a.w;
    sm = wred_sum(sm); ss = wred_sum(ss);
    if ((tid & 63) == 0) { red[tid >> 6] = sm; red[4 + (tid >> 6)] = ss; }
    __syncthreads();
    sm = red[0] + red[1] + red[2] + red[3];
    ss = red[4] + red[5] + red[6] + red[7];
    float mean = sm * (1.0f / D_);
    float rstd = rsqrtf(ss * (1.0f / D_) - mean * mean + 1e-5f);
    float4 gv = *(const float4*)(g + c);
    float4 bv = *(const float4*)(b + c);
    float o0 = (a.x - mean) * rstd * gv.x + bv.x;
    float o1 = (a.y - mean) * rstd * gv.y + bv.y;
    float o2 = (a.z - mean) * rstd * gv.z + bv.z;
    float o3 = (a.w - mean) * rstd * gv.w + bv.w;
    if (OUTF) {
        *(float4*)((float*)out + (size_t)row * D_ + c) = make_float4(o0, o1, o2, o3);
    } else {
        bf16x4 o; o[0] = (bf16)o0; o[1] = (bf16)o1; o[2] = (bf16)o2; o[3] = (bf16)o3;
        *(bf16x4*)((bf16*)out + (size_t)row * D_ + c) = o;
    }
}

// ---- fused weight prep (+ bkv accumulation in WkvTg branch) ----
__device__ __forceinline__ void wt_tile(const float* __restrict__ in, int R, int C,
                                        bf16* __restrict__ out, int bx, int by,
                                        const float* __restrict__ sc,
                                        const float* __restrict__ bm,
                                        float* __restrict__ bkv) {
    __shared__ float t[32][33];
    int c0 = bx * 32, r0 = by * 32;
    int tx = threadIdx.x & 31, ty = threadIdx.x >> 5;
#pragma unroll
    for (int i = 0; i < 4; i++)
        t[ty + i * 8][tx] = in[(size_t)(r0 + ty + i * 8) * C + c0 + tx];
    __syncthreads();
    float scale = sc ? sc[r0 + tx] : 1.0f;
#pragma unroll
    for (int i = 0; i < 4; i++)
        out[(size_t)(c0 + ty + i * 8) * R + r0 + tx] = (bf16)(t[tx][ty + i * 8] * scale);
    if (bm && ty == 0) {
        float s = 0.0f;
#pragma unroll
        for (int r = 0; r < 32; r++) s += bm[r0 + r] * t[r][tx];
        atomicAdd(&bkv[c0 + tx], s);
    }
}

__global__ __launch_bounds__(256) void wprep_k(const float* __restrict__ wq,
                                               const float* __restrict__ wkv,
                                               const float* __restrict__ wo,
                                               const float* __restrict__ w1,
                                               const float* __restrict__ w2,
                                               const float* __restrict__ gm,
                                               const float* __restrict__ bm,
                                               float* __restrict__ bkv,
                                               bf16* __restrict__ BcatQ,   // rows 0..511
                                               bf16* __restrict__ BcatKV,  // rows 512..1535
                                               bf16* __restrict__ WkvTg,
                                               bf16* __restrict__ WoT,
                                               bf16* __restrict__ W1T,
                                               bf16* __restrict__ W2T) {
    int id = blockIdx.x;
    if (id < 512)            wt_tile(wq, D_, INNER_, BcatQ, id & 15, id >> 4, nullptr, nullptr, nullptr);
    else if (id < 1536)  { int i = id - 512;  wt_tile(wkv, D_, 2 * INNER_, BcatKV, i & 31, i >> 5, nullptr, nullptr, nullptr); }
    else if (id < 2560)  { int i = id - 1536; wt_tile(wkv, D_, 2 * INNER_, WkvTg, i & 31, i >> 5, gm, bm, bkv); }
    else if (id < 3072)  { int i = id - 2560; wt_tile(wo, INNER_, D_, WoT, i & 31, i >> 5, nullptr, nullptr, nullptr); }
    else if (id < 7168)  { int i = id - 3072; wt_tile(w1, D_, FF_, W1T, i & 127, i >> 7, nullptr, nullptr, nullptr); }
    else                 { int i = id - 7168; wt_tile(w2, FF_, D_, W2T, i & 31, i >> 5, nullptr, nullptr, nullptr); }
}

// ======== KV GEMM: 256x256 8-phase pipelined NT (proven R6 schedule) ========
// A=xhat (32768 x 1024), B=WkvTg (1024 x 1024). Epilogue splits columns:
//   cb<512  -> K part into KVb (ld 512), row = bt*1088 + j, +bias
//   cb>=512 -> V part TRANSPOSED into vt[(bt*8+h)*64+dh][j], +bias
__global__ __launch_bounds__(512, 1) void gemm_kv(const bf16* __restrict__ Ag,
                                                  const bf16* __restrict__ Bg,
                                                  bf16* __restrict__ KVb,
                                                  bf16* __restrict__ vt,
                                                  const float* __restrict__ bias) {
    __shared__ bf16 lds[2][32768];   // [buf][Alo 0 | Ahi 8192 | Blo 16384 | Bhi 24576]
    const int lda = D_, ldb = D_;
    const int tid = threadIdx.x;
    const int w = tid >> 6, lane = tid & 63;
    const int wm = w >> 2, wn = w & 3;
    const size_t m0 = (size_t)blockIdx.x * 256;
    const size_t n0 = (size_t)blockIdx.y * 256;
    const int nt = 16;   // K=1024, BK=64

    const int p0 = (w * 2) * 64 + lane, p1 = p0 + 64;
    const int sr0 = p0 >> 3, sk0 = ((p0 & 7) ^ (sr0 & 7)) * 8;
    const int sr1 = p1 >> 3, sk1 = ((p1 & 7) ^ (sr1 & 7)) * 8;
    const int scw0 = (w * 2) * 512, scw1 = scw0 + 512;

    auto STAGE = [&](const bf16* g, int ld, size_t row0, int k0, bf16* bufb, int rb) {
        gload_lds16(g + (row0 + sr0) * (size_t)ld + k0 + sk0, bufb + rb + scw0);
        gload_lds16(g + (row0 + sr1) * (size_t)ld + k0 + sk1, bufb + rb + scw1);
    };

    const int fr = lane & 15;
    const int pK0 = (((lane >> 4)) ^ (fr & 7)) * 8;
    const int pK1 = ((4 + (lane >> 4)) ^ (fr & 7)) * 8;
    const size_t aoff = (size_t)(wm * 128 + fr) * 64;
    const size_t boff = 16384 + (size_t)(wn * 64 + fr) * 64;

    f32x4 acc[8][4];
#pragma unroll
    for (int i = 0; i < 8; i++)
#pragma unroll
        for (int j = 0; j < 4; j++)
#pragma unroll
            for (int r = 0; r < 4; r++) acc[i][j][r] = 0.0f;

    STAGE(Bg, ldb, n0,       0, lds[0], 16384);
    STAGE(Bg, ldb, n0 + 128, 0, lds[0], 24576);
    STAGE(Ag, lda, m0,       0, lds[0], 0);
    STAGE(Ag, lda, m0 + 128, 0, lds[0], 8192);
    STAGE(Bg, ldb, n0,       64, lds[1], 16384);
    STAGE(Bg, ldb, n0 + 128, 64, lds[1], 24576);
    STAGE(Ag, lda, m0,       64, lds[1], 0);
    asm volatile("s_waitcnt vmcnt(6)");
    BARRIER();

    for (int t = 0; t < nt; ++t) {
        const bf16* lb = lds[t & 1];
        bf16* lbw = lds[t & 1];
        bf16* lbn = lds[(t + 1) & 1];
        const int kt1 = (t + 1) << 6, kt2 = (t + 2) << 6;
        bf16x8 bfr[4][2];

        {
#pragma unroll
            for (int j = 0; j < 4; j++) {
                bfr[j][0] = *(const bf16x8*)(lb + boff + j * 1024 + pK0);
                bfr[j][1] = *(const bf16x8*)(lb + boff + j * 1024 + pK1);
            }
            bf16x8 a00 = *(const bf16x8*)(lb + aoff + 0 * 1024 + pK0);
            bf16x8 a01 = *(const bf16x8*)(lb + aoff + 0 * 1024 + pK1);
            bf16x8 a10 = *(const bf16x8*)(lb + aoff + 1 * 1024 + pK0);
            bf16x8 a11 = *(const bf16x8*)(lb + aoff + 1 * 1024 + pK1);
            if (t + 1 < nt) STAGE(Ag, lda, m0 + 128, kt1, lbn, 8192);
            BARRIER();
            asm volatile("s_waitcnt lgkmcnt(0)");
            __builtin_amdgcn_s_setprio(1);
#pragma unroll
            for (int j = 0; j < 4; j++) {
                acc[0][j] = __builtin_amdgcn_mfma_f32_16x16x32_bf16(a00, bfr[j][0], acc[0][j], 0, 0, 0);
                acc[0][j] = __builtin_amdgcn_mfma_f32_16x16x32_bf16(a01, bfr[j][1], acc[0][j], 0, 0, 0);
                acc[1][j] = __builtin_amdgcn_mfma_f32_16x16x32_bf16(a10, bfr[j][0], acc[1][j], 0, 0, 0);
                acc[1][j] = __builtin_amdgcn_mfma_f32_16x16x32_bf16(a11, bfr[j][1], acc[1][j], 0, 0, 0);
            }
            __builtin_amdgcn_s_setprio(0);
            BARRIER();
        }
        {
            bf16x8 a00 = *(const bf16x8*)(lb + aoff + 2 * 1024 + pK0);
            bf16x8 a01 = *(const bf16x8*)(lb + aoff + 2 * 1024 + pK1);
            bf16x8 a10 = *(const bf16x8*)(lb + aoff + 3 * 1024 + pK0);
            bf16x8 a11 = *(const bf16x8*)(lb + aoff + 3 * 1024 + pK1);
            if (t + 2 < nt) STAGE(Bg, ldb, n0, kt2, lbw, 16384);
            BARRIER();
            asm volatile("s_waitcnt lgkmcnt(0)");
            __builtin_amdgcn_s_setprio(1);
#pragma unroll
            for (int j = 0; j < 4; j++) {
                acc[2][j] = __builtin_amdgcn_mfma_f32_16x16x32_bf16(a00, bfr[j][0], acc[2][j], 0, 0, 0);
                acc[2][j] = __builtin_amdgcn_mfma_f32_16x16x32_bf16(a01, bfr[j][1], acc[2][j], 0, 0, 0);
                acc[3][j] = __builtin_amdgcn_mfma_f32_16x16x32_bf16(a10, bfr[j][0], acc[3][j], 0, 0, 0);
                acc[3][j] = __builtin_amdgcn_mfma_f32_16x16x32_bf16(a11, bfr[j][1], acc[3][j], 0, 0, 0);
            }
            __builtin_amdgcn_s_setprio(0);
            BARRIER();
        }
        {
            bf16x8 a00 = *(const bf16x8*)(lb + aoff + 4 * 1024 + pK0);
            bf16x8 a01 = *(const bf16x8*)(lb + aoff + 4 * 1024 + pK1);
            bf16x8 a10 = *(const bf16x8*)(lb + aoff + 5 * 1024 + pK0);
            bf16x8 a11 = *(const bf16x8*)(lb + aoff + 5 * 1024 + pK1);
            if (t + 2 < nt) STAGE(Bg, ldb, n0 + 128, kt2, lbw, 24576);
            BARRIER();
            asm volatile("s_waitcnt lgkmcnt(0)");
            __builtin_amdgcn_s_setprio(1);
#pragma unroll
            for (int j = 0; j < 4; j++) {
                acc[4][j] = __builtin_amdgcn_mfma_f32_16x16x32_bf16(a00, bfr[j][0], acc[4][j], 0, 0, 0);
                acc[4][j] = __builtin_amdgcn_mfma_f32_16x16x32_bf16(a01, bfr[j][1], acc[4][j], 0, 0, 0);
                acc[5][j] = __builtin_amdgcn_mfma_f32_16x16x32_bf16(a10, bfr[j][0], acc[5][j], 0, 0, 0);
                acc[5][j] = __builtin_amdgcn_mfma_f32_16x16x32_bf16(a11, bfr[j][1], acc[5][j], 0, 0, 0);
            }
            __builtin_amdgcn_s_setprio(0);
            BARRIER();
        }
        {
            bf16x8 a00 = *(const bf16x8*)(lb + aoff + 6 * 1024 + pK0);
            bf16x8 a01 = *(const bf16x8*)(lb + aoff + 6 * 1024 + pK1);
            bf16x8 a10 = *(const bf16x8*)(lb + aoff + 7 * 1024 + pK0);
            bf16x8 a11 = *(const bf16x8*)(lb + aoff + 7 * 1024 + pK1);
            if (t + 2 < nt) STAGE(Ag, lda, m0, kt2, lbw, 0);
            BARRIER();
            asm volatile("s_waitcnt lgkmcnt(0)");
            __builtin_amdgcn_s_setprio(1);
#pragma unroll
            for (int j = 0; j < 4; j++) {
                acc[6][j] = __builtin_amdgcn_mfma_f32_16x16x32_bf16(a00, bfr[j][0], acc[6][j], 0, 0, 0);
                acc[6][j] = __builtin_amdgcn_mfma_f32_16x16x32_bf16(a01, bfr[j][1], acc[6][j], 0, 0, 0);
                acc[7][j] = __builtin_amdgcn_mfma_f32_16x16x32_bf16(a10, bfr[j][0], acc[7][j], 0, 0, 0);
                acc[7][j] = __builtin_amdgcn_mfma_f32_16x16x32_bf16(a11, bfr[j][1], acc[7][j], 0, 0, 0);
            }
            __builtin_amdgcn_s_setprio(0);
            if (t < nt - 2)       { asm volatile("s_waitcnt vmcnt(6)"); }
            else if (t == nt - 2) { asm volatile("s_waitcnt vmcnt(0)"); }
            BARRIER();
        }
    }

    // epilogue: K -> KVb (ld 512), V -> vt transposed
    const int fq = (lane >> 4) * 4;
#pragma unroll
    for (int i = 0; i < 8; i++)
#pragma unroll
        for (int j = 0; j < 4; j++) {
            size_t cb = n0 + wn * 64 + j * 16 + fr;
            float bv = bias[cb];
            size_t mb = m0 + wm * 128 + i * 16 + fq;
            if (cb < 512) {
#pragma unroll
                for (int r = 0; r < 4; r++) {
                    size_t m = mb + r;
                    size_t rb = m + ((m >> 10) << 6);
                    KVb[rb * 512 + cb] = (bf16)(acc[i][j][r] + bv);
                }
            } else {
                int hh = ((int)cb - 512) >> 6, dh = ((int)cb - 512) & 63;
                size_t bt = mb >> 10, jl = mb & 1023;
                bf16x4 v4;
#pragma unroll
                for (int r = 0; r < 4; r++) v4[r] = (bf16)(acc[i][j][r] + bv);
                *(bf16x4*)(vt + ((bt * 8 + hh) * 64 + dh) * (size_t)NKV_ + jl) = v4;
            }
        }
}

// ======== FF GEMM: 128x256, pipelined-frag 4-phase schedule (R8, kept) ========
// MODE 3: bf16 gelu out. MODE 4: fp32 split-K partial (czs stride).
template<int MODE>
__global__ __launch_bounds__(512, 1) void gemm_ff(const bf16* __restrict__ Ag, int lda,
                                                  const bf16* __restrict__ Bg, int ldb,
                                                  void* __restrict__ C, int ldc,
                                                  int K, long long czs) {
    __shared__ bf16 lds[2][24576];   // [buf][A 0..8191 | Blo 8192 | Bhi 16384]
    const int tid = threadIdx.x;
    const int w = tid >> 6, lane = tid & 63;
    const int wm = w >> 2, wn = w & 3;
    const size_t m0 = (size_t)blockIdx.x * 128;
    const size_t n0 = (size_t)blockIdx.y * 256;
    const int klen = K / gridDim.z;
    const int koff = blockIdx.z * klen;
    const int nt = klen >> 6;

    const int p0 = (w * 2) * 64 + lane, p1 = p0 + 64;
    const int sr0 = p0 >> 3, sk0 = ((p0 & 7) ^ (sr0 & 7)) * 8;
    const int sr1 = p1 >> 3, sk1 = ((p1 & 7) ^ (sr1 & 7)) * 8;
    const int scw0 = (w * 2) * 512, scw1 = scw0 + 512;

    auto STAGE = [&](const bf16* g, int ld, size_t row0, int k0, bf16* bufb, int rb) {
        gload_lds16(g + (row0 + sr0) * (size_t)ld + k0 + sk0, bufb + rb + scw0);
        gload_lds16(g + (row0 + sr1) * (size_t)ld + k0 + sk1, bufb + rb + scw1);
    };

    const int fr = lane & 15;
    const int pK0 = (((lane >> 4)) ^ (fr & 7)) * 8;
    const int pK1 = ((4 + (lane >> 4)) ^ (fr & 7)) * 8;
    const size_t aoff = (size_t)(wm * 64 + fr) * 64;
    const size_t boff = 8192 + (size_t)(wn * 64 + fr) * 64;

    f32x4 acc[4][4];
#pragma unroll
    for (int i = 0; i < 4; i++)
#pragma unroll
        for (int j = 0; j < 4; j++)
#pragma unroll
            for (int r = 0; r < 4; r++) acc[i][j][r] = 0.0f;

    bf16x8 aX[2], aY[2], bA[4][2], bB[4][2];

    auto LDA1 = [&](const bf16* lb, int i0, bf16x8 (&d)[2]) {
        d[0] = *(const bf16x8*)(lb + aoff + (size_t)i0 * 1024 + pK0);
        d[1] = *(const bf16x8*)(lb + aoff + (size_t)i0 * 1024 + pK1);
    };
    auto LDB8 = [&](const bf16* lb, bf16x8 (&bb)[4][2]) {
#pragma unroll
        for (int j = 0; j < 4; j++) {
            bb[j][0] = *(const bf16x8*)(lb + boff + j * 1024 + pK0);
            bb[j][1] = *(const bf16x8*)(lb + boff + j * 1024 + pK1);
        }
    };
    auto MM1 = [&](int i0, bf16x8 (&a)[2], bf16x8 (&bb)[4][2]) {
        __builtin_amdgcn_s_setprio(1);
#pragma unroll
        for (int j = 0; j < 4; j++) {
            acc[i0][j] = __builtin_amdgcn_mfma_f32_16x16x32_bf16(a[0], bb[j][0], acc[i0][j], 0, 0, 0);
            acc[i0][j] = __builtin_amdgcn_mfma_f32_16x16x32_bf16(a[1], bb[j][1], acc[i0][j], 0, 0, 0);
        }
        __builtin_amdgcn_s_setprio(0);
    };

    // prologue: tile0 {A,Blo,Bhi} + tile1 {Blo,Bhi} = 10 loads
    STAGE(Ag, lda, m0,       koff,      lds[0], 0);
    STAGE(Bg, ldb, n0,       koff,      lds[0], 8192);
    STAGE(Bg, ldb, n0 + 128, koff,      lds[0], 16384);
    STAGE(Bg, ldb, n0,       koff + 64, lds[1], 8192);
    STAGE(Bg, ldb, n0 + 128, koff + 64, lds[1], 16384);
    asm volatile("s_waitcnt vmcnt(4)");   // tile0 landed
    BARRIER();
    LDB8(lds[0], bA);
    LDA1(lds[0], 0, aX);

    auto tile4 = [&](const bf16* lb, bf16* lbn, bf16x8 (&BU)[4][2], bf16x8 (&BL)[4][2], int t) {
        bf16* lbw = (bf16*)lb;
        // ph0: MFMA row 0; prefetch row 1; stage A(t+1)->other buf
        LDA1(lb, 1, aY);
        if (t + 1 < nt) STAGE(Ag, lda, m0, koff + ((t + 1) << 6), lbn, 0);
        MM1(0, aX, BU);
        ENDPH();
        // ph1: row 1; prefetch row 2; stage Blo(t+2)->cur
        LDA1(lb, 2, aX);
        if (t + 2 < nt) STAGE(Bg, ldb, n0, koff + ((t + 2) << 6), lbw, 8192);
        MM1(1, aY, BU);
        ENDPH();
        // ph2: row 2; prefetch row 3; stage Bhi(t+2); tile-end vmcnt
        LDA1(lb, 3, aY);
        if (t + 2 < nt) STAGE(Bg, ldb, n0 + 128, koff + ((t + 2) << 6), lbw, 16384);
        MM1(2, aX, BU);
        __builtin_amdgcn_sched_barrier(0);
        asm volatile("s_waitcnt lgkmcnt(0)");
        __builtin_amdgcn_sched_barrier(0);
        // outstanding: A(t+1), Blo(t+2), Bhi(t+2) = 6 loads
        if (t < nt - 2)       { asm volatile("s_waitcnt vmcnt(4)"); }   // A(t+1) landed
        else if (t == nt - 2) { asm volatile("s_waitcnt vmcnt(0)"); }
        BARRIER();
        // ph3: row 3; prefetch tile-t+1 ph0 frags
        if (t + 1 < nt) { LDB8(lbn, BL); LDA1(lbn, 0, aX); }
        MM1(3, aY, BU);
        ENDPH();
    };

    for (int t = 0; t < nt; t += 2) {
        tile4(lds[0], lds[1], bA, bB, t);
        tile4(lds[1], lds[0], bB, bA, t + 1);
    }

    const int fq = (lane >> 4) * 4;
#pragma unroll
    for (int i = 0; i < 4; i++)
#pragma unroll
        for (int j = 0; j < 4; j++) {
            size_t cb = n0 + wn * 64 + j * 16 + fr;
            size_t mb = m0 + wm * 64 + i * 16 + fq;
#pragma unroll
            for (int r = 0; r < 4; r++) {
                float v = acc[i][j][r];
                if (MODE == 4) {
                    ((float*)C + blockIdx.z * czs)[(mb + r) * (size_t)ldc + cb] = v;
                } else {
                    ((bf16*)C)[(mb + r) * (size_t)ldc + cb] = (bf16)gelu_f(v);
                }
            }
        }
}

// ---- 128x128 NT GEMM (swizzled LDS) ----
// MODE 4: fp32 store (split-K partial, czs stride).
// CMAP 3: cb<512 -> qb*scale; 512<=cb<1024 -> KVb K-part (ld 512, lat rows);
//         cb>=1024 -> vt transposed (lat rows).
template<int MODE, int CMAP>
__global__ __launch_bounds__(256) void gemm128(const bf16* __restrict__ A, int lda,
                                               const bf16* __restrict__ Bw, int ldb,
                                               void* __restrict__ C, int ldc,
                                               int K, float scale,
                                               long long czs, void* __restrict__ C2,
                                               void* __restrict__ C3) {
    __shared__ bf16 As[128 * 32];
    __shared__ bf16 Bs[128 * 32];
    const int tid = threadIdx.x;
    const int wave = tid >> 6;
    const int lane = tid & 63;
    const size_t m0 = (size_t)blockIdx.x * 128;
    const size_t n0 = (size_t)blockIdx.y * 128;
    const int wm = (wave >> 1) * 64;
    const int wn = (wave & 1) * 64;

    const int klen = K / gridDim.z;
    const int koff = blockIdx.z * klen;

    const int r0 = tid >> 2;
    const int c0 = ((tid & 3) ^ ((tid >> 3) & 3)) * 8;
    const bf16* ga0 = A + (m0 + r0) * lda + c0 + koff;
    const bf16* ga1 = A + (m0 + r0 + 64) * lda + c0 + koff;
    const bf16* gb0 = Bw + (n0 + r0) * ldb + c0 + koff;
    const bf16* gb1 = Bw + (n0 + r0 + 64) * ldb + c0 + koff;
    bf16* la0 = As + wave * 512;
    bf16* la1 = As + 2048 + wave * 512;
    bf16* lb0 = Bs + wave * 512;
    bf16* lb1 = Bs + 2048 + wave * 512;

    f32x4 acc[4][4];
#pragma unroll
    for (int i = 0; i < 4; i++)
#pragma unroll
        for (int j = 0; j < 4; j++)
#pragma unroll
            for (int r = 0; r < 4; r++) acc[i][j][r] = 0.0f;

    const int fr = lane & 15;
    const int q = lane >> 4;
    const int sw = (q ^ ((fr >> 1) & 3)) * 8;

    for (int kt = 0; kt < klen; kt += 32) {
        gload_lds16(ga0 + kt, la0);
        gload_lds16(ga1 + kt, la1);
        gload_lds16(gb0 + kt, lb0);
        gload_lds16(gb1 + kt, lb1);
        __syncthreads();
        bf16x8 af[4], bfv[4];
#pragma unroll
        for (int i = 0; i < 4; i++) {
            af[i]  = *(const bf16x8*)(As + (wm + i * 16 + fr) * 32 + sw);
            bfv[i] = *(const bf16x8*)(Bs + (wn + i * 16 + fr) * 32 + sw);
        }
#pragma unroll
        for (int i = 0; i < 4; i++)
#pragma unroll
            for (int j = 0; j < 4; j++)
                acc[i][j] = __builtin_amdgcn_mfma_f32_16x16x32_bf16(af[i], bfv[j], acc[i][j], 0, 0, 0);
        __syncthreads();
    }

    const int fq = (lane >> 4) * 4;
#pragma unroll
    for (int i = 0; i < 4; i++)
#pragma unroll
        for (int j = 0; j < 4; j++) {
            size_t cb = n0 + wn + j * 16 + fr;
            size_t mb = m0 + wm + i * 16 + fq;
            if (CMAP == 3) {
                if (cb < 512) {
#pragma unroll
                    for (int r = 0; r < 4; r++)
                        ((bf16*)C)[(mb + r) * 512 + cb] = (bf16)(acc[i][j][r] * scale);
                } else if (cb < 1024) {
#pragma unroll
                    for (int r = 0; r < 4; r++) {
                        size_t m = mb + r;
                        size_t rb = (m >> 6) * (size_t)NKV_ + 1024 + (m & 63);
                        ((bf16*)C2)[rb * 512 + (cb - 512)] = (bf16)acc[i][j][r];
                    }
                } else {
                    int hh = ((int)cb - 1024) >> 6, dh = ((int)cb - 1024) & 63;
                    size_t bt = mb >> 6, jl = 1024 + (mb & 63);
                    bf16x4 v4;
#pragma unroll
                    for (int r = 0; r < 4; r++) v4[r] = (bf16)acc[i][j][r];
                    *(bf16x4*)((bf16*)C3 + ((bt * 8 + hh) * 64 + dh) * (size_t)NKV_ + jl) = v4;
                }
            } else {
#pragma unroll
                for (int r = 0; r < 4; r++) {
                    float v = acc[i][j][r];
                    if (MODE == 4) {
                        ((float*)C + blockIdx.z * czs)[(mb + r) * ldc + cb] = v;
                    } else {
                        ((bf16*)C)[(mb + r) * ldc + cb] = (bf16)v;
                    }
                }
            }
        }
}

// ======== fused attention: QK^T + online softmax + PV, one block per z ========
__global__ __launch_bounds__(256, 2) void attn_k(const bf16* __restrict__ qb,
                                                 const bf16* __restrict__ KVb,
                                                 const bf16* __restrict__ vt,
                                                 bf16* __restrict__ ob) {
    __shared__ float comb[4][64 * 66];
    __shared__ float sc[4][64];
    __shared__ float mw[4][64], lw[4][64];
    const int z = blockIdx.x, bt = z >> 3, h = z & 7;
    const int tid = threadIdx.x, w = tid >> 6, lane = tid & 63;
    const int fr = lane & 15, g = lane >> 4;
    const bf16* Qz = qb + (size_t)(bt * 64) * INNER_ + h * DH_;
    const bf16* Kz = KVb + (size_t)bt * NKV_ * 512 + h * DH_;   // K rows, ld 512
    const bf16* Vz = vt + (size_t)z * (DH_ * NKV_);
    bf16* Pw = (bf16*)(&comb[w][0]);

    bf16x8 qf[4][2];
#pragma unroll
    for (int nj = 0; nj < 4; nj++)
#pragma unroll
        for (int ks = 0; ks < 2; ks++)
            qf[nj][ks] = *(const bf16x8*)(Qz + (size_t)(fr + 16 * nj) * INNER_ + g * 8 + ks * 32);

    f32x4 acc_o[4][4];
#pragma unroll
    for (int i = 0; i < 4; i++)
#pragma unroll
        for (int j = 0; j < 4; j++)
#pragma unroll
            for (int r = 0; r < 4; r++) acc_o[i][j][r] = 0.0f;
    float m_reg[4] = {-INFINITY, -INFINITY, -INFINITY, -INFINITY};
    float l_reg[4] = {0.0f, 0.0f, 0.0f, 0.0f};

    const int nch = (w == 0) ? 5 : 4;
    for (int ci = 0; ci < nch; ci++) {
        const int kc0 = (w + ci * 4) * 64;
        f32x4 s[4][4];
#pragma unroll
        for (int i = 0; i < 4; i++)
#pragma unroll
            for (int j = 0; j < 4; j++)
#pragma unroll
                for (int r = 0; r < 4; r++) s[i][j][r] = 0.0f;
#pragma unroll
        for (int ks = 0; ks < 2; ks++) {
            bf16x8 kf[4];
#pragma unroll
            for (int mi = 0; mi < 4; mi++)
                kf[mi] = *(const bf16x8*)(Kz + (size_t)(kc0 + fr + 16 * mi) * 512 + g * 8 + ks * 32);
#pragma unroll
            for (int mi = 0; mi < 4; mi++)
#pragma unroll
                for (int nj = 0; nj < 4; nj++)
                    s[mi][nj] = __builtin_amdgcn_mfma_f32_16x16x32_bf16(kf[mi], qf[nj][ks], s[mi][nj], 0, 0, 0);
        }
        float pmax[4];
#pragma unroll
        for (int nj = 0; nj < 4; nj++) {
            float mx = s[0][nj][0];
#pragma unroll
            for (int mi = 0; mi < 4; mi++)
#pragma unroll
                for (int r = 0; r < 4; r++) mx = fmaxf(mx, s[mi][nj][r]);
            mx = fmaxf(mx, __shfl_xor(mx, 16, 64));
            mx = fmaxf(mx, __shfl_xor(mx, 32, 64));
            pmax[nj] = mx;
        }
        bool grew = (pmax[0] > m_reg[0]) || (pmax[1] > m_reg[1]) ||
                    (pmax[2] > m_reg[2]) || (pmax[3] > m_reg[3]);
        if (__any(grew ? 1 : 0)) {
            float so[4];
#pragma unroll
            for (int nj = 0; nj < 4; nj++) {
                float mn = fmaxf(m_reg[nj], pmax[nj]);
                so[nj] = __expf(m_reg[nj] - mn);
                m_reg[nj] = mn;
                l_reg[nj] *= so[nj];
            }
            if (g == 0) {
#pragma unroll
                for (int nj = 0; nj < 4; nj++) sc[w][fr + 16 * nj] = so[nj];
            }
            asm volatile("s_waitcnt lgkmcnt(0)" ::: "memory");
#pragma unroll
            for (int mi = 0; mi < 4; mi++)
#pragma unroll
                for (int r = 0; r < 4; r++) {
                    float sq = sc[w][16 * mi + 4 * g + r];
#pragma unroll
                    for (int jd = 0; jd < 4; jd++) acc_o[mi][jd][r] *= sq;
                }
        }
        float psum[4] = {0.0f, 0.0f, 0.0f, 0.0f};
#pragma unroll
        for (int mi = 0; mi < 4; mi++)
#pragma unroll
            for (int nj = 0; nj < 4; nj++) {
                bf16x4 pb4;
#pragma unroll
                for (int r = 0; r < 4; r++) {
                    float pv = __expf(s[mi][nj][r] - m_reg[nj]);
                    psum[nj] += pv;
                    pb4[r] = (bf16)pv;
                }
                *(bf16x4*)(Pw + (size_t)(fr + 16 * nj) * 72 + 16 * mi + 4 * g) = pb4;
            }
#pragma unroll
        for (int nj = 0; nj < 4; nj++) {
            float ps = psum[nj];
            ps += __shfl_xor(ps, 16, 64);
            ps += __shfl_xor(ps, 32, 64);
            l_reg[nj] += ps;
        }
        asm volatile("s_waitcnt lgkmcnt(0)" ::: "memory");
#pragma unroll
        for (int ks = 0; ks < 2; ks++) {
            bf16x8 af[4], vf[4];
#pragma unroll
            for (int mi = 0; mi < 4; mi++)
                af[mi] = *(const bf16x8*)(Pw + (size_t)(fr + 16 * mi) * 72 + g * 8 + ks * 32);
#pragma unroll
            for (int jd = 0; jd < 4; jd++)
                vf[jd] = *(const bf16x8*)(Vz + (size_t)(fr + 16 * jd) * NKV_ + kc0 + g * 8 + ks * 32);
#pragma unroll
            for (int mi = 0; mi < 4; mi++)
#pragma unroll
                for (int jd = 0; jd < 4; jd++)
                    acc_o[mi][jd] = __builtin_amdgcn_mfma_f32_16x16x32_bf16(af[mi], vf[jd], acc_o[mi][jd], 0, 0, 0);
        }
    }

    if (g == 0) {
#pragma unroll
        for (int nj = 0; nj < 4; nj++) {
            mw[w][fr + 16 * nj] = m_reg[nj];
            lw[w][fr + 16 * nj] = l_reg[nj];
        }
    }
    asm volatile("s_waitcnt lgkmcnt(0)" ::: "memory");
#pragma unroll
    for (int mi = 0; mi < 4; mi++)
#pragma unroll
        for (int jd = 0; jd < 4; jd++)
#pragma unroll
            for (int r = 0; r < 4; r++)
                comb[w][(16 * mi + 4 * g + r) * 66 + fr + 16 * jd] = acc_o[mi][jd][r];
    __syncthreads();
    {
        int q = tid >> 2, d0 = (tid & 3) * 16;
        float M = fmaxf(fmaxf(mw[0][q], mw[1][q]), fmaxf(mw[2][q], mw[3][q]));
        float al[4], l = 0.0f;
#pragma unroll
        for (int ww = 0; ww < 4; ww++) { al[ww] = __expf(mw[ww][q] - M); l += al[ww] * lw[ww][q]; }
        float inv = 1.0f / l;
        bf16 outv[16];
#pragma unroll
        for (int dd = 0; dd < 16; dd++) {
            float o = 0.0f;
#pragma unroll
            for (int ww = 0; ww < 4; ww++) o += comb[ww][q * 66 + d0 + dd] * al[ww];
            outv[dd] = (bf16)(o * inv);
        }
        bf16* dst = ob + (size_t)(bt * 64 + q) * INNER_ + h * 64 + d0;
        *(bf16x8*)dst = *(bf16x8*)outv;
        *(bf16x8*)(dst + 8) = *(bf16x8*)(outv + 8);
    }
}

// ---- host side ----
extern "C" void kernel_launch(void* const* d_in, const int* in_sizes, int n_in,
                              void* d_out, int out_size, void* d_ws, size_t ws_size,
                              hipStream_t stream) {
    const float* x       = (const float*)d_in[0];
    const float* latents = (const float*)d_in[1];
    const float* fe      = (const float*)d_in[2];
    const float* g_media = (const float*)d_in[3];
    const float* b_media = (const float*)d_in[4];
    const float* g_lat   = (const float*)d_in[5];
    const float* b_lat   = (const float*)d_in[6];
    const float* Wq      = (const float*)d_in[7];
    const float* Wkv     = (const float*)d_in[8];
    const float* Wo      = (const float*)d_in[9];
    const float* g_ff    = (const float*)d_in[10];
    const float* b_ff    = (const float*)d_in[11];
    const float* W1      = (const float*)d_in[12];
    const float* W2      = (const float*)d_in[13];
    const float* g_out   = (const float*)d_in[14];
    const float* b_out   = (const float*)d_in[15];

    char* p = (char*)d_ws;
    auto alloc = [&](size_t bytes) { char* r = p; p += (bytes + 255) & ~(size_t)255; return r; };
    bf16*  xhat = (bf16*)alloc((size_t)MROWS_ * D_ * 2);          // 67 MB
    float* lat  = (float*)alloc((size_t)2048 * D_ * 4);           // 8 MB
    bf16*  lnl  = (bf16*)alloc((size_t)2048 * D_ * 2);            // 4 MB
    bf16*  qb   = (bf16*)alloc((size_t)2048 * INNER_ * 2);        // 2 MB
    bf16*  KVb  = (bf16*)alloc((size_t)KVROWS_ * 512 * 2);        // 36 MB (K-part only, ld 512)
    bf16*  vt   = (bf16*)alloc((size_t)ZB_ * DH_ * NKV_ * 2);     // 36 MB
    bf16*  ob   = (bf16*)alloc((size_t)2048 * INNER_ * 2);        // 2 MB
    bf16*  Bcat = (bf16*)alloc((size_t)1536 * D_ * 2);            // 3 MB
    bf16*  WkvTg= (bf16*)alloc((size_t)D_ * D_ * 2);
    bf16*  WoT  = (bf16*)alloc((size_t)D_ * INNER_ * 2);
    bf16*  W1T  = (bf16*)alloc((size_t)FF_ * D_ * 2);
    bf16*  W2T  = (bf16*)alloc((size_t)D_ * FF_ * 2);
    float* bkv  = (float*)alloc(1024 * 4);
    float* ffp  = (float*)alloc((size_t)4 * 2048 * D_ * 4);       // 32 MB
    bf16*  ffh  = vt;            // alias: vt dead once attn done (16.8 MB <= 35.7 MB)

    xhat_k<<<MROWS_, 256, 0, stream>>>(x, fe, xhat);
    latinit_k<<<2048, 256, 0, stream>>>(latents, lat);
    ln_k<0><<<2048, 256, 0, stream>>>(lat, g_lat, b_lat, lnl);   // layer-0 latent LN

    const long long PS = (long long)2048 * D_;

    for (int l = 0; l < L_; l++) {
        const float* gm = g_media + (size_t)l * D_;
        const float* bm = b_media + (size_t)l * D_;
        const float* gf = g_ff + (size_t)l * D_;
        const float* bf_ = b_ff + (size_t)l * D_;
        const float* wq = Wq + (size_t)l * D_ * INNER_;
        const float* wkv = Wkv + (size_t)l * D_ * 2 * INNER_;
        const float* wo = Wo + (size_t)l * INNER_ * D_;
        const float* w1 = W1 + (size_t)l * D_ * FF_;
        const float* w2 = W2 + (size_t)l * FF_ * D_;

        hipMemsetAsync(bkv, 0, 1024 * 4, stream);
        wprep_k<<<11264, 256, 0, stream>>>(wq, wkv, wo, w1, w2, gm, bm, bkv,
                                           Bcat, Bcat + (size_t)512 * D_, WkvTg, WoT, W1T, W2T);

        // KV x-part: K -> KVb, V -> vt (transposed), +bkv   [8-phase 256², proven]
        gemm_kv<<<dim3(128, 4), 512, 0, stream>>>(xhat, WkvTg, KVb, vt, bkv);
        // merged: q = (lnl@WqT)*scale; KV lat rows: K -> KVb, V -> vt
        gemm128<0, 3><<<dim3(16, 12), 256, 0, stream>>>(
            lnl, D_, Bcat, D_, qb, 0, D_, 0.125f, 0, KVb, vt);

        // fused attention -> ob
        attn_k<<<ZB_, 256, 0, stream>>>(qb, KVb, vt, ob);

        // Wo split-K 2 -> fp32 partials
        gemm128<4, 0><<<dim3(16, 8, 2), 256, 0, stream>>>(
            ob, INNER_, WoT, INNER_, ffp, D_, INNER_, 1.0f, PS, nullptr, nullptr);
        // lat += partials; lnl = LN(lat; gf,bf)
        accln_k<2, 0><<<2048, 256, 0, stream>>>(lat, ffp, PS, gf, bf_, lnl);

        // FF1: ffh = gelu(lnl @ W1T)   [pipelined 128x256]
        gemm_ff<3><<<dim3(16, 16), 512, 0, stream>>>(
            lnl, D_, W1T, D_, ffh, FF_, D_, 0);
        // FF2 split-K 4 -> fp32 partials   [pipelined 128x256]
        gemm_ff<4><<<dim3(16, 4, 4), 512, 0, stream>>>(
            ffh, FF_, W2T, FF_, ffp, D_, FF_, PS);
        // lat += partials; next-layer latent LN (or final LN -> d_out)
        if (l < L_ - 1) {
            accln_k<4, 0><<<2048, 256, 0, stream>>>(lat, ffp, PS,
                g_lat + (size_t)(l + 1) * D_, b_lat + (size_t)(l + 1) * D_, lnl);
        } else {
            accln_k<4, 1><<<2048, 256, 0, stream>>>(lat, ffp, PS, g_out, b_out, (float*)d_out);
        }
    }
}